// Round 11
// baseline (840.539 us; speedup 1.0000x reference)
//
#include <hip/hip_runtime.h>
#include <hip/hip_cooperative_groups.h>

namespace cg = cooperative_groups;

// GeometryOptimalTransport: B=4, N=M=4096, C=128
// Sinkhorn (3 iters) over log_K(m,n) = -dist2/eps masked to -1e9, then
// attn-weighted gather of source feats.
//
// R2: validity is iteration-invariant -> precompute adjacency once; run all
// lse updates + output on the ~3% dense structure. Finite NEG_INF=-1e9
// contamination is closed-form:
//   - row with 0 valid entries => u = +1e9 EXACTLY (ulp(1e9)=64)
//   - such rows contribute exp(0) to EVERY column lse => per-batch count cc
//   - all other invalid entries underflow to exactly 0 in fp32.
// Journal: compaction costs ~60us in ANY form -> permuted bitmap (bit k of
// lane L's word <=> partner n=(k>>1)*128+2L+(k&1)). Sweep ~60-70us is an
// EMPIRICAL FLOOR (invariant to loads/LDS/compaction/block count/extra exp).
// sweep10 fuses sweep + u1 + in-block bit-transpose (verified butterfly).
// R12: sorted 4-row output REGRESSED (gather set 118KB >> 32KB L1) ->
// output3 one-block-per-row stays (measured at the 35TB/s L2 roof).
// R13 post-mortem: 128-thr lse split NEUTRAL (114 vs 105us for the chain) ->
// divergent-tail theory dead. Every gather kernel here runs at 25-35%
// VALUBusy, 3-5x roofline, stall invariant to 5 ablations -> remaining
// untested theory: PER-DISPATCH FIXED COST (~15us: ramp/drain/serialization;
// R9's half-block sweep at unchanged time supports it).
// R14 (this round): fuse the 5 lse dispatches into ONE cooperative kernel
// (1024 blocks x 256 thr, launch_bounds(256,4) -> 4 blocks/CU co-resident,
// ~40 VGPR, 0 LDS), grid.sync() between the 5 phases, R11-proven wave-per-
// row/col bodies, grid-stride 4 units/wave/phase. Removes 4 dispatch
// boundaries and keeps u/v/bitmaps hot in L2.

constexpr int   BB = 4;
constexpr int   NN = 4096;
constexpr int   MM = 4096;
constexpr int   CC = 128;
constexpr float kNegInf    = -1000000000.0f;
constexpr float kThresh2   = 0.04f;                 // 0.2^2
constexpr float kNegInvEps = -(1.0f / 0.01000001f); // -(1/(EPSILON+1e-8))

__device__ inline float wave_reduce_sum(float x) {
#pragma unroll
  for (int off = 32; off > 0; off >>= 1)
    x += __shfl_xor(x, off, 64);
  return x;
}
__device__ inline float wave_reduce_max(float x) {
#pragma unroll
  for (int off = 32; off > 0; off >>= 1)
    x = fmaxf(x, __shfl_xor(x, off, 64));
  return x;
}

// ---------------------------------------------------------------------------
// FAST PATH (needs ~17 MB workspace)
// ---------------------------------------------------------------------------

// zero v, fold masks into locs (invalid -> far sentinel; DIFFERENT sentinels
// per side so two invalid points are never "close").
__global__ __launch_bounds__(256) void prep_kernel(
    const float* __restrict__ sloc, const float* __restrict__ tloc,
    const int* __restrict__ sm, const int* __restrict__ tm,
    float* __restrict__ v, int* __restrict__ ecnt,
    float2* __restrict__ slm, float2* __restrict__ tlm)
{
  int i = blockIdx.x * 256 + threadIdx.x;
  if (i < BB * NN) {
    v[i] = 0.0f;
    float2 s = ((const float2*)sloc)[i];
    slm[i] = sm[i] ? s : make_float2(1.0e9f, 1.0e9f);
    float2 t = ((const float2*)tloc)[i];
    tlm[i] = tm[i] ? t : make_float2(3.0e9f, 3.0e9f);
    if (i < BB) ecnt[i] = 0;
  }
}

// Fused sweep + u1 + bit-transpose. One block per (batch b, L'): 1024 thr =
// 16 waves, wave wid owns rows m = {base, base+1, base+128, base+129},
// base = wid*256 + 2L'. Lane L, iter i tests partners i*128+2L, i*128+2L+1;
// bit k of lane L's word <=> n=(k>>1)*128+2L+(k&1). After the sweep: row_bm
// + u1 (v0=0) + ecnt census, then the block stages its 64x64 word tile in
// LDS (rotated slots) and each wave butterfly-transposes 4 column tiles.
__global__ __launch_bounds__(1024) void sweep10_kernel(
    const float2* __restrict__ slm, const float2* __restrict__ tlm,
    unsigned long long* __restrict__ row_bm,
    unsigned long long* __restrict__ col_bm,
    int* __restrict__ ecnt, float* __restrict__ u)
{
  __shared__ unsigned long long tile[64 * 64];   // 32 KB

  const int b    = blockIdx.x >> 6;
  const int Lp   = blockIdx.x & 63;              // L'
  const int tid  = threadIdx.x;
  const int lane = tid & 63;
  const int wid  = tid >> 6;                     // 0..15
  const int base = b * 4096 + wid * 256 + 2 * Lp;
  const int m0 = base, m1 = base + 1, m2 = base + 128, m3 = base + 129;

  const float2 a0 = tlm[m0];
  const float2 a1 = tlm[m1];
  const float2 a2 = tlm[m2];
  const float2 a3 = tlm[m3];
  const float4* __restrict__ bl4 = (const float4*)(slm + (size_t)b * 4096);

  unsigned long long w0 = 0, w1 = 0, w2 = 0, w3 = 0;
  float s0 = 0.0f, s1 = 0.0f, s2 = 0.0f, s3 = 0.0f;
#pragma unroll 8
  for (int i = 0; i < 32; ++i) {
    float4 q = bl4[i * 64 + lane];
#define SWTEST(aa, ww, ss)                                         \
    do {                                                           \
      float dx0 = (aa).x - q.x, dy0 = (aa).y - q.y;                \
      float dx1 = (aa).x - q.z, dy1 = (aa).y - q.w;                \
      float d0 = fmaf(dy0, dy0, dx0 * dx0);                        \
      float d1 = fmaf(dy1, dy1, dx1 * dx1);                        \
      bool p0 = d0 < kThresh2;                                     \
      bool p1 = d1 < kThresh2;                                     \
      ww = (ww >> 2) | (p0 ? (1ull << 62) : 0ull)                  \
                     | (p1 ? (1ull << 63) : 0ull);                 \
      float e0 = __expf(d0 * kNegInvEps);                          \
      float e1 = __expf(d1 * kNegInvEps);                          \
      ss += p0 ? e0 : 0.0f;                                        \
      ss += p1 ? e1 : 0.0f;                                        \
    } while (0)
    SWTEST(a0, w0, s0);
    SWTEST(a1, w1, s1);
    SWTEST(a2, w2, s2);
    SWTEST(a3, w3, s3);
#undef SWTEST
  }

  row_bm[(size_t)m0 * 64 + lane] = w0;
  row_bm[(size_t)m1 * 64 + lane] = w1;
  row_bm[(size_t)m2 * 64 + lane] = w2;
  row_bm[(size_t)m3 * 64 + lane] = w3;

  // stage tile rows (rho = wid*4 + j), rotated slot (lane+rho)&63
  {
    const int r0 = wid * 4;
    tile[(r0 + 0) * 64 + ((lane + r0 + 0) & 63)] = w0;
    tile[(r0 + 1) * 64 + ((lane + r0 + 1) & 63)] = w1;
    tile[(r0 + 2) * 64 + ((lane + r0 + 2) & 63)] = w2;
    tile[(r0 + 3) * 64 + ((lane + r0 + 3) & 63)] = w3;
  }

  // u1 = -log(ssum) per row (v0 = 0); ssum==0 <=> empty row (valid terms
  // are exp(t), t >= -4, so a non-empty row's sum cannot underflow).
  s0 = wave_reduce_sum(s0);
  s1 = wave_reduce_sum(s1);
  s2 = wave_reduce_sum(s2);
  s3 = wave_reduce_sum(s3);
  if (lane == 0) {
    u[m0] = (s0 == 0.0f) ? 1.0e9f : -__logf(s0);
    u[m1] = (s1 == 0.0f) ? 1.0e9f : -__logf(s1);
    u[m2] = (s2 == 0.0f) ? 1.0e9f : -__logf(s2);
    u[m3] = (s3 == 0.0f) ? 1.0e9f : -__logf(s3);
    int e = (s0 == 0.0f) + (s1 == 0.0f) + (s2 == 0.0f) + (s3 == 0.0f);
    if (e) atomicAdd(&ecnt[b], e);
  }
  __syncthreads();

  // transpose: wave wid handles Lt = wid*4..+3 (verified butterfly from R9)
  unsigned long long* __restrict__ cb = col_bm + ((size_t)b << 12) * 64;
#pragma unroll
  for (int i = 0; i < 4; ++i) {
    const int Lt = wid * 4 + i;
    unsigned long long w = tile[lane * 64 + ((Lt + lane) & 63)];
#define BTSTEP(S, MLO)                                                  \
    do {                                                                \
      unsigned long long t = __shfl_xor(w, S, 64);                      \
      w = (lane & S) ? ((w & ~(MLO)) | ((t >> S) & (MLO)))              \
                     : ((w & (MLO)) | ((t & (MLO)) << S));              \
    } while (0)
    BTSTEP(32, 0x00000000FFFFFFFFull);
    BTSTEP(16, 0x0000FFFF0000FFFFull);
    BTSTEP(8,  0x00FF00FF00FF00FFull);
    BTSTEP(4,  0x0F0F0F0F0F0F0F0Full);
    BTSTEP(2,  0x3333333333333333ull);
    BTSTEP(1,  0x5555555555555555ull);
#undef BTSTEP
    const int n = ((lane >> 1) << 7) + 2 * Lt + (lane & 1);
    cb[(size_t)n * 64 + Lp] = w;
  }
}

// Cooperative fused lse chain: phases v1, u2, v2, u3, v3 with grid.sync()
// between. 1024 blocks x 256 thr (4 blocks/CU co-resident), 4096 waves,
// one wave per row/col, 4 units per wave per phase (grid-stride).
// Bodies identical to the R11-proven lse kernels (64-bit word per lane,
// ctz-enumerate; no max pass: |t| << 87).
__global__ __launch_bounds__(256, 4) void coop_lse_kernel(
    const float2* __restrict__ slm, const float2* __restrict__ tlm,
    const unsigned long long* __restrict__ row_bm,
    const unsigned long long* __restrict__ col_bm,
    const int* __restrict__ smask, const int* __restrict__ ecnt,
    float* __restrict__ u, float* __restrict__ v)
{
  cg::grid_group grid = cg::this_grid();
  const int lane  = threadIdx.x & 63;
  const int gwave = blockIdx.x * 4 + (threadIdx.x >> 6);   // 0..4095

#pragma unroll 1
  for (int phase = 0; phase < 5; ++phase) {
    if ((phase & 1) == 0) {
      // col phase: v[col] = !sv ? 0 : -log(sum exp(t) + cc)
#pragma unroll 1
      for (int col = gwave; col < BB * NN; col += 4096) {
        const int b  = col >> 12;
        const bool sv = smask[col] != 0;
        float s_l = 0.0f;
        if (sv) {
          unsigned long long w = col_bm[(size_t)col * 64 + lane];
          const float2 a = slm[col];
          const float2* __restrict__ tl = tlm + (size_t)b * MM;
          const float*  __restrict__ ub = u + (size_t)b * MM;
          while (w) {
            int k = (int)__builtin_ctzll(w);
            w &= w - 1;
            int m = ((k >> 1) << 7) + 2 * lane + (k & 1);
            float2 s = tl[m];
            float dx = a.x - s.x, dy = a.y - s.y;
            float t = fmaf(dy, dy, dx * dx) * kNegInvEps + ub[m];
            s_l += __expf(t);
          }
        }
        float ssum = wave_reduce_sum(s_l);
        if (lane == 0) {
          if (!sv) {
            v[col] = 0.0f;
          } else {
            float tot = ssum + (float)ecnt[b];  // contamination = exp(0) each
            v[col] = (tot == 0.0f) ? 1.0e9f : -__logf(tot);
          }
        }
      }
    } else {
      // row phase: u[row] = -log(sum exp(t)), +1e9 if empty
#pragma unroll 1
      for (int row = gwave; row < BB * MM; row += 4096) {
        const int b = row >> 12;
        unsigned long long w = row_bm[(size_t)row * 64 + lane];
        const float2 a = tlm[row];
        const float2* __restrict__ sl = slm + (size_t)b * NN;
        const float*  __restrict__ vb = v + (size_t)b * NN;
        float s_l = 0.0f;
        while (w) {
          int k = (int)__builtin_ctzll(w);
          w &= w - 1;
          int n = ((k >> 1) << 7) + 2 * lane + (k & 1);
          float2 s = sl[n];
          float dx = a.x - s.x, dy = a.y - s.y;
          float t = fmaf(dy, dy, dx * dx) * kNegInvEps + vb[n];
          s_l += __expf(t);
        }
        float ssum = wave_reduce_sum(s_l);
        if (lane == 0) u[row] = (ssum == 0.0f) ? 1.0e9f : -__logf(ssum);
      }
    }
    if (phase < 4) grid.sync();
  }
}

// out[row,:] = sum_j attn_j * feats[n_j,:], one block per row (PROVEN 55us,
// at the 35TB/s L2 roof). Phase 1: 256 threads extract the row's bitmap
// (thread t owns the (t&3)-th 16-bit quarter of word t>>2), compute attn,
// append to LDS via atomic slot. Phase 2: 8 groups x 32 lanes gather feats.
__global__ __launch_bounds__(256) void output3_kernel(
    const float2* __restrict__ tlm, const float2* __restrict__ slm,
    const unsigned long long* __restrict__ row_bm,
    const float* __restrict__ u, const float* __restrict__ v,
    const float* __restrict__ feats, float* __restrict__ out)
{
  __shared__ float s_attn[1024];
  __shared__ unsigned short s_id[1024];
  __shared__ float4 s_red[256];
  __shared__ int s_cnt;

  const int j   = blockIdx.x;
  const int row = (j & 7) * 2048 + (j >> 3);
  const int tid = threadIdx.x;
  const int b   = row >> 12;
  if (tid == 0) s_cnt = 0;
  __syncthreads();

  {
    const int L  = tid >> 2;
    const int qp = tid & 3;
    unsigned long long w = row_bm[(size_t)row * 64 + L];
    unsigned wq = (unsigned)(unsigned short)(w >> (qp * 16));
    if (wq) {
      const float um = u[row];
      const float2 a = tlm[row];
      const float2* __restrict__ sl = slm + (size_t)b * NN;
      const float*  __restrict__ vb = v + (size_t)b * NN;
      while (wq) {
        int kk = (int)__builtin_ctz(wq);
        wq &= wq - 1;
        int k = qp * 16 + kk;
        int n = ((k >> 1) << 7) + 2 * L + (k & 1);
        float2 s = sl[n];
        float dx = a.x - s.x, dy = a.y - s.y;
        float aw = __expf(fmaf(dy, dy, dx * dx) * kNegInvEps + um + vb[n]);
        int p = atomicAdd(&s_cnt, 1);
        if (p < 1024) { s_attn[p] = aw; s_id[p] = (unsigned short)n; }
      }
    }
  }
  __syncthreads();

  int cnt = s_cnt;
  if (cnt > 1024) cnt = 1024;             // realistic max ~330, never hit
  float4* op = (float4*)(out + (size_t)row * CC);
  if (cnt == 0) {                         // covers !tgt_valid and !has_source
    if (tid < 32) op[tid] = make_float4(0.f, 0.f, 0.f, 0.f);
    return;
  }

  const int g = tid >> 5, l = tid & 31;
  const float4* __restrict__ fb = (const float4*)(feats + (size_t)b * NN * CC);
  float4 acc = make_float4(0.f, 0.f, 0.f, 0.f);
  for (int jj = g; jj < cnt; jj += 8) {
    float aw = s_attn[jj];
    int   n  = s_id[jj];
    float4 f = fb[(size_t)n * 32 + l];
    acc.x = fmaf(aw, f.x, acc.x);
    acc.y = fmaf(aw, f.y, acc.y);
    acc.z = fmaf(aw, f.z, acc.z);
    acc.w = fmaf(aw, f.w, acc.w);
  }
  s_red[tid] = acc;
  __syncthreads();
  if (tid < 32) {
    float4 r = s_red[tid];
#pragma unroll
    for (int gg = 1; gg < 8; ++gg) {
      float4 p = s_red[gg * 32 + tid];
      r.x += p.x; r.y += p.y; r.z += p.z; r.w += p.w;
    }
    op[tid] = r;
  }
}

// ---------------------------------------------------------------------------
// FALLBACK PATH (round-1 kernels, ~128 KB workspace) — used if ws too small
// ---------------------------------------------------------------------------

__global__ __launch_bounds__(256) void init_v_kernel(float* __restrict__ v) {
  int i = blockIdx.x * 256 + threadIdx.x;
  if (i < BB * NN) v[i] = 0.0f;
}

__global__ __launch_bounds__(256) void u_update_kernel(
    const float* __restrict__ src_locs, const float* __restrict__ tgt_locs,
    const int* __restrict__ src_valid, const int* __restrict__ tgt_valid,
    const float* __restrict__ v, float* __restrict__ u)
{
  const int lane = threadIdx.x & 63;
  const int row  = blockIdx.x * 4 + (threadIdx.x >> 6);
  const int b    = row / MM;
  const float tx = tgt_locs[row * 2 + 0];
  const float ty = tgt_locs[row * 2 + 1];
  const bool  tv = tgt_valid[row] != 0;
  const float2* __restrict__ sl  = (const float2*)(src_locs + (size_t)b * NN * 2);
  const float*  __restrict__ vb  = v + (size_t)b * NN;
  const int*    __restrict__ svb = src_valid + (size_t)b * NN;
  float mx = -3.0e38f;
#pragma unroll 4
  for (int i = 0; i < NN / 64; ++i) {
    int n = i * 64 + lane;
    float2 s = sl[n];
    float dx = tx - s.x, dy = ty - s.y;
    float d2 = dx * dx + dy * dy;
    bool valid = (d2 < kThresh2) & tv & (svb[n] != 0);
    float t = (valid ? d2 * kNegInvEps : kNegInf) + vb[n];
    mx = fmaxf(mx, t);
  }
  mx = wave_reduce_max(mx);
  float s = 0.0f;
#pragma unroll 4
  for (int i = 0; i < NN / 64; ++i) {
    int n = i * 64 + lane;
    float2 sc = sl[n];
    float dx = tx - sc.x, dy = ty - sc.y;
    float d2 = dx * dx + dy * dy;
    bool valid = (d2 < kThresh2) & tv & (svb[n] != 0);
    float t = (valid ? d2 * kNegInvEps : kNegInf) + vb[n];
    s += __expf(t - mx);
  }
  s = wave_reduce_sum(s);
  if (lane == 0) u[row] = -(mx + __logf(s));
}

__global__ __launch_bounds__(256) void v_update_kernel(
    const float* __restrict__ src_locs, const float* __restrict__ tgt_locs,
    const int* __restrict__ src_valid, const int* __restrict__ tgt_valid,
    const float* __restrict__ u, float* __restrict__ v)
{
  const int lane = threadIdx.x & 63;
  const int col  = blockIdx.x * 4 + (threadIdx.x >> 6);
  const int b    = col / NN;
  const float sx = src_locs[col * 2 + 0];
  const float sy = src_locs[col * 2 + 1];
  const bool  sv = src_valid[col] != 0;
  const float2* __restrict__ tl  = (const float2*)(tgt_locs + (size_t)b * MM * 2);
  const float*  __restrict__ ub  = u + (size_t)b * MM;
  const int*    __restrict__ tvb = tgt_valid + (size_t)b * MM;
  float mx = -3.0e38f;
#pragma unroll 4
  for (int i = 0; i < MM / 64; ++i) {
    int m = i * 64 + lane;
    float2 t2 = tl[m];
    float dx = t2.x - sx, dy = t2.y - sy;
    float d2 = dx * dx + dy * dy;
    bool valid = (d2 < kThresh2) & sv & (tvb[m] != 0);
    float t = (valid ? d2 * kNegInvEps : kNegInf) + ub[m];
    mx = fmaxf(mx, t);
  }
  mx = wave_reduce_max(mx);
  float s = 0.0f;
#pragma unroll 4
  for (int i = 0; i < MM / 64; ++i) {
    int m = i * 64 + lane;
    float2 t2 = tl[m];
    float dx = t2.x - sx, dy = t2.y - sy;
    float d2 = dx * dx + dy * dy;
    bool valid = (d2 < kThresh2) & sv & (tvb[m] != 0);
    float t = (valid ? d2 * kNegInvEps : kNegInf) + ub[m];
    s += __expf(t - mx);
  }
  s = wave_reduce_sum(s);
  if (lane == 0) v[col] = sv ? -(mx + __logf(s)) : 0.0f;
}

__global__ __launch_bounds__(256) void output_kernel(
    const float* __restrict__ src_locs, const float* __restrict__ tgt_locs,
    const int* __restrict__ src_valid, const int* __restrict__ tgt_valid,
    const float* __restrict__ u, const float* __restrict__ v,
    const float* __restrict__ feats, float* __restrict__ out)
{
  __shared__ float s_attn[NN];
  __shared__ int   s_idx[NN];
  __shared__ int   s_cnt;
  __shared__ float s_part[CC];
  const int row = blockIdx.x;
  const int b   = row / MM;
  const int tid = threadIdx.x;
  if (tid == 0) s_cnt = 0;
  __syncthreads();
  const float tx = tgt_locs[row * 2 + 0];
  const float ty = tgt_locs[row * 2 + 1];
  const bool  tv = tgt_valid[row] != 0;
  const float um = u[row];
  const float2* __restrict__ sl  = (const float2*)(src_locs + (size_t)b * NN * 2);
  const float*  __restrict__ vb  = v + (size_t)b * NN;
  const int*    __restrict__ svb = src_valid + (size_t)b * NN;
#pragma unroll 4
  for (int i = 0; i < NN / 256; ++i) {
    int n = i * 256 + tid;
    float2 s = sl[n];
    float dx = tx - s.x, dy = ty - s.y;
    float d2 = dx * dx + dy * dy;
    bool valid = (d2 < kThresh2) & tv & (svb[n] != 0);
    if (valid) {
      float a = __expf((d2 * kNegInvEps + um) + vb[n]);
      int p = atomicAdd(&s_cnt, 1);
      s_attn[p] = a;
      s_idx[p]  = n;
    }
  }
  __syncthreads();
  const int cnt = s_cnt;
  const int g = tid >> 7;
  const int c = tid & (CC - 1);
  const float* __restrict__ fb = feats + (size_t)b * NN * CC;
  float acc = 0.0f;
  for (int j = g; j < cnt; j += 2) {
    float a = s_attn[j];
    int   n = s_idx[j];
    acc = fmaf(a, fb[(size_t)n * CC + c], acc);
  }
  if (g == 1) s_part[c] = acc;
  __syncthreads();
  if (g == 0) {
    float r = (cnt > 0) ? (acc + s_part[c]) : 0.0f;
    out[(size_t)row * CC + c] = r;
  }
}

// ---------------------------------------------------------------------------

extern "C" void kernel_launch(void* const* d_in, const int* in_sizes, int n_in,
                              void* d_out, int out_size, void* d_ws, size_t ws_size,
                              hipStream_t stream) {
  const float* feats = (const float*)d_in[0];
  const float* sloc  = (const float*)d_in[1];
  const float* tloc  = (const float*)d_in[2];
  const int*   smask = (const int*)d_in[3];
  const int*   tmask = (const int*)d_in[4];
  float* out = (float*)d_out;

  // workspace layout (fast path): ~17 MB
  char* p = (char*)d_ws;
  float* u_   = (float*)p;            p += (size_t)BB * MM * 4;
  float* v_   = (float*)p;            p += (size_t)BB * NN * 4;
  int* ecnt   = (int*)p;              p += 256;
  float2* slm = (float2*)p;           p += (size_t)BB * NN * 8;
  float2* tlm = (float2*)p;           p += (size_t)BB * MM * 8;
  unsigned long long* row_bm = (unsigned long long*)p; p += (size_t)BB * MM * 64 * 8;
  unsigned long long* col_bm = (unsigned long long*)p; p += (size_t)BB * NN * 64 * 8;
  size_t required = (size_t)(p - (char*)d_ws);

  if (ws_size >= required) {
    prep_kernel<<<(BB * NN + 255) / 256, 256, 0, stream>>>(
        sloc, tloc, smask, tmask, v_, ecnt, slm, tlm);
    // fused sweep: row_bm + col_bm (in-block transpose) + u1 + ecnt
    sweep10_kernel<<<BB * 64, 1024, 0, stream>>>(
        slm, tlm, row_bm, col_bm, ecnt, u_);
    // u1 done; fused chain v1,u2,v2,u3,v3 as ONE cooperative dispatch
    {
      void* cargs[] = {
        (void*)&slm, (void*)&tlm, (void*)&row_bm, (void*)&col_bm,
        (void*)&smask, (void*)&ecnt, (void*)&u_, (void*)&v_
      };
      hipLaunchCooperativeKernel((const void*)coop_lse_kernel,
                                 dim3(1024), dim3(256), cargs, 0, stream);
    }
    output3_kernel<<<BB * MM, 256, 0, stream>>>(tlm, slm, row_bm,
                                                u_, v_, feats, out);
  } else {
    // fallback: round-1 path (dense re-sweeps), needs only 128 KB
    float* u = (float*)d_ws;
    float* v = u + (size_t)BB * MM;
    init_v_kernel<<<(BB * NN + 255) / 256, 256, 0, stream>>>(v);
    for (int it = 0; it < 3; ++it) {
      u_update_kernel<<<BB * MM / 4, 256, 0, stream>>>(sloc, tloc, smask, tmask, v, u);
      v_update_kernel<<<BB * NN / 4, 256, 0, stream>>>(sloc, tloc, smask, tmask, u, v);
    }
    output_kernel<<<BB * MM, 256, 0, stream>>>(sloc, tloc, smask, tmask, u, v, feats, out);
  }
}

// Round 12
// 231.838 us; speedup vs baseline: 3.6255x; 3.6255x over previous
//
#include <hip/hip_runtime.h>

// GeometryOptimalTransport: B=4, N=M=4096, C=128
// Sinkhorn (3 iters) over log_K(m,n) = -dist2/eps masked to -1e9, then
// attn-weighted gather of source feats.
//
// R2: validity is iteration-invariant -> precompute adjacency once; run all
// lse updates + output on the ~3% dense structure. Finite NEG_INF=-1e9
// contamination is closed-form:
//   - row with 0 valid entries => u = +1e9 EXACTLY (ulp(1e9)=64)
//   - such rows contribute exp(0) to EVERY column lse => per-batch count cc
//   - all other invalid entries underflow to exactly 0 in fp32.
// Journal of falsified theories (keep for future sessions):
//   - compaction in ANY form costs ~60us (R5/R6) -> permuted bitmap instead
//     (bit k of lane L's word <=> partner n=(k>>1)*128+2L+(k&1))
//   - sweep ~60-70us is an EMPIRICAL FLOOR: invariant to load volume (R5),
//     LDS staging (R8), compaction removal (R7), block count (R9), fused
//     exp work (R11). Stall cause never identified by counters.
//   - sorted 4-row output REGRESSED (R12): gather set 118KB >> 32KB L1.
//   - 128-thr lse split NEUTRAL (R13): divergent tail was not the gate.
//   - cooperative grid.sync costs ~135us PER SYNC on MI355X (R14: 654us vs
//     114us for 5 stream dispatches; VALUBusy 2.8%) -> stream boundaries
//     are the CHEAP way to order phases. NEVER use grid.sync here.
// R15 (this round): revert to the best-known composition, all components
// individually measured: prep 3 + sweep10 71.7 (fused sweep+u1+in-block
// bit-transpose, verified butterfly) + R11-proven lse chain ~105 (5
// dispatches, one wave/row, ctz-enumerate, no max pass since |t| << 87)
// + output3 55 (one block/row, at the 35TB/s L2 roof).

constexpr int   BB = 4;
constexpr int   NN = 4096;
constexpr int   MM = 4096;
constexpr int   CC = 128;
constexpr float kNegInf    = -1000000000.0f;
constexpr float kThresh2   = 0.04f;                 // 0.2^2
constexpr float kNegInvEps = -(1.0f / 0.01000001f); // -(1/(EPSILON+1e-8))

__device__ inline float wave_reduce_sum(float x) {
#pragma unroll
  for (int off = 32; off > 0; off >>= 1)
    x += __shfl_xor(x, off, 64);
  return x;
}
__device__ inline float wave_reduce_max(float x) {
#pragma unroll
  for (int off = 32; off > 0; off >>= 1)
    x = fmaxf(x, __shfl_xor(x, off, 64));
  return x;
}

// ---------------------------------------------------------------------------
// FAST PATH (needs ~17 MB workspace)
// ---------------------------------------------------------------------------

// zero v, fold masks into locs (invalid -> far sentinel; DIFFERENT sentinels
// per side so two invalid points are never "close").
__global__ __launch_bounds__(256) void prep_kernel(
    const float* __restrict__ sloc, const float* __restrict__ tloc,
    const int* __restrict__ sm, const int* __restrict__ tm,
    float* __restrict__ v, int* __restrict__ ecnt,
    float2* __restrict__ slm, float2* __restrict__ tlm)
{
  int i = blockIdx.x * 256 + threadIdx.x;
  if (i < BB * NN) {
    v[i] = 0.0f;
    float2 s = ((const float2*)sloc)[i];
    slm[i] = sm[i] ? s : make_float2(1.0e9f, 1.0e9f);
    float2 t = ((const float2*)tloc)[i];
    tlm[i] = tm[i] ? t : make_float2(3.0e9f, 3.0e9f);
    if (i < BB) ecnt[i] = 0;
  }
}

// Fused sweep + u1 + bit-transpose. One block per (batch b, L'): 1024 thr =
// 16 waves, wave wid owns rows m = {base, base+1, base+128, base+129},
// base = wid*256 + 2L'. Lane L, iter i tests partners i*128+2L, i*128+2L+1;
// bit k of lane L's word <=> n=(k>>1)*128+2L+(k&1). After the sweep: row_bm
// + u1 (v0=0) + ecnt census, then the block stages its 64x64 word tile in
// LDS (rotated slots) and each wave butterfly-transposes 4 column tiles.
__global__ __launch_bounds__(1024) void sweep10_kernel(
    const float2* __restrict__ slm, const float2* __restrict__ tlm,
    unsigned long long* __restrict__ row_bm,
    unsigned long long* __restrict__ col_bm,
    int* __restrict__ ecnt, float* __restrict__ u)
{
  __shared__ unsigned long long tile[64 * 64];   // 32 KB

  const int b    = blockIdx.x >> 6;
  const int Lp   = blockIdx.x & 63;              // L'
  const int tid  = threadIdx.x;
  const int lane = tid & 63;
  const int wid  = tid >> 6;                     // 0..15
  const int base = b * 4096 + wid * 256 + 2 * Lp;
  const int m0 = base, m1 = base + 1, m2 = base + 128, m3 = base + 129;

  const float2 a0 = tlm[m0];
  const float2 a1 = tlm[m1];
  const float2 a2 = tlm[m2];
  const float2 a3 = tlm[m3];
  const float4* __restrict__ bl4 = (const float4*)(slm + (size_t)b * 4096);

  unsigned long long w0 = 0, w1 = 0, w2 = 0, w3 = 0;
  float s0 = 0.0f, s1 = 0.0f, s2 = 0.0f, s3 = 0.0f;
#pragma unroll 8
  for (int i = 0; i < 32; ++i) {
    float4 q = bl4[i * 64 + lane];
#define SWTEST(aa, ww, ss)                                         \
    do {                                                           \
      float dx0 = (aa).x - q.x, dy0 = (aa).y - q.y;                \
      float dx1 = (aa).x - q.z, dy1 = (aa).y - q.w;                \
      float d0 = fmaf(dy0, dy0, dx0 * dx0);                        \
      float d1 = fmaf(dy1, dy1, dx1 * dx1);                        \
      bool p0 = d0 < kThresh2;                                     \
      bool p1 = d1 < kThresh2;                                     \
      ww = (ww >> 2) | (p0 ? (1ull << 62) : 0ull)                  \
                     | (p1 ? (1ull << 63) : 0ull);                 \
      float e0 = __expf(d0 * kNegInvEps);                          \
      float e1 = __expf(d1 * kNegInvEps);                          \
      ss += p0 ? e0 : 0.0f;                                        \
      ss += p1 ? e1 : 0.0f;                                        \
    } while (0)
    SWTEST(a0, w0, s0);
    SWTEST(a1, w1, s1);
    SWTEST(a2, w2, s2);
    SWTEST(a3, w3, s3);
#undef SWTEST
  }

  row_bm[(size_t)m0 * 64 + lane] = w0;
  row_bm[(size_t)m1 * 64 + lane] = w1;
  row_bm[(size_t)m2 * 64 + lane] = w2;
  row_bm[(size_t)m3 * 64 + lane] = w3;

  // stage tile rows (rho = wid*4 + j), rotated slot (lane+rho)&63
  {
    const int r0 = wid * 4;
    tile[(r0 + 0) * 64 + ((lane + r0 + 0) & 63)] = w0;
    tile[(r0 + 1) * 64 + ((lane + r0 + 1) & 63)] = w1;
    tile[(r0 + 2) * 64 + ((lane + r0 + 2) & 63)] = w2;
    tile[(r0 + 3) * 64 + ((lane + r0 + 3) & 63)] = w3;
  }

  // u1 = -log(ssum) per row (v0 = 0); ssum==0 <=> empty row (valid terms
  // are exp(t), t >= -4, so a non-empty row's sum cannot underflow).
  s0 = wave_reduce_sum(s0);
  s1 = wave_reduce_sum(s1);
  s2 = wave_reduce_sum(s2);
  s3 = wave_reduce_sum(s3);
  if (lane == 0) {
    u[m0] = (s0 == 0.0f) ? 1.0e9f : -__logf(s0);
    u[m1] = (s1 == 0.0f) ? 1.0e9f : -__logf(s1);
    u[m2] = (s2 == 0.0f) ? 1.0e9f : -__logf(s2);
    u[m3] = (s3 == 0.0f) ? 1.0e9f : -__logf(s3);
    int e = (s0 == 0.0f) + (s1 == 0.0f) + (s2 == 0.0f) + (s3 == 0.0f);
    if (e) atomicAdd(&ecnt[b], e);
  }
  __syncthreads();

  // transpose: wave wid handles Lt = wid*4..+3 (verified butterfly from R9)
  unsigned long long* __restrict__ cb = col_bm + ((size_t)b << 12) * 64;
#pragma unroll
  for (int i = 0; i < 4; ++i) {
    const int Lt = wid * 4 + i;
    unsigned long long w = tile[lane * 64 + ((Lt + lane) & 63)];
#define BTSTEP(S, MLO)                                                  \
    do {                                                                \
      unsigned long long t = __shfl_xor(w, S, 64);                      \
      w = (lane & S) ? ((w & ~(MLO)) | ((t >> S) & (MLO)))              \
                     : ((w & (MLO)) | ((t & (MLO)) << S));              \
    } while (0)
    BTSTEP(32, 0x00000000FFFFFFFFull);
    BTSTEP(16, 0x0000FFFF0000FFFFull);
    BTSTEP(8,  0x00FF00FF00FF00FFull);
    BTSTEP(4,  0x0F0F0F0F0F0F0F0Full);
    BTSTEP(2,  0x3333333333333333ull);
    BTSTEP(1,  0x5555555555555555ull);
#undef BTSTEP
    const int n = ((lane >> 1) << 7) + 2 * Lt + (lane & 1);
    cb[(size_t)n * 64 + Lp] = w;
  }
}

// u[row] = -log(sum_j exp(logK_j + v[n_j])), +1e9 if no valid entries.
// One wave per row (R11-proven). Lane L ctz-enumerates its own bitmap word.
// No max pass: all t bounded (|t| << 87), exp cannot over/underflow.
__global__ __launch_bounds__(256) void lse_row_kernel(
    const float2* __restrict__ tlm, const float2* __restrict__ slm,
    const unsigned long long* __restrict__ row_bm,
    const float* __restrict__ v, float* __restrict__ u)
{
  const int lane = threadIdx.x & 63;
  const int j    = blockIdx.x;
  const int row  = (j & 7) * 2048 + (j >> 3) * 4 + (threadIdx.x >> 6);
  const int b    = row >> 12;
  unsigned long long w = row_bm[(size_t)row * 64 + lane];
  const float2 a = tlm[row];
  const float2* __restrict__ sl = slm + (size_t)b * NN;
  const float*  __restrict__ vb = v + (size_t)b * NN;
  float s_l = 0.0f;
  while (w) {
    int k = (int)__builtin_ctzll(w);
    w &= w - 1;
    int n = ((k >> 1) << 7) + 2 * lane + (k & 1);
    float2 s = sl[n];
    float dx = a.x - s.x, dy = a.y - s.y;
    float t = fmaf(dy, dy, dx * dx) * kNegInvEps + vb[n];
    s_l += __expf(t);
  }
  float ssum = wave_reduce_sum(s_l);
  if (lane == 0) u[row] = (ssum == 0.0f) ? 1.0e9f : -__logf(ssum);
}

// v[col] = !sv ? 0 : -log(sum exp(t) + cc); +1e9 if both empty.
__global__ __launch_bounds__(256) void lse_col_kernel(
    const float2* __restrict__ slm, const float2* __restrict__ tlm,
    const unsigned long long* __restrict__ col_bm,
    const int* __restrict__ smask, const int* __restrict__ ecnt,
    const float* __restrict__ u, float* __restrict__ v)
{
  const int lane = threadIdx.x & 63;
  const int j    = blockIdx.x;
  const int col  = (j & 7) * 2048 + (j >> 3) * 4 + (threadIdx.x >> 6);
  if (!smask[col]) { if (lane == 0) v[col] = 0.0f; return; }
  const int b = col >> 12;
  unsigned long long w = col_bm[(size_t)col * 64 + lane];
  const float2 a = slm[col];
  const float2* __restrict__ tl = tlm + (size_t)b * MM;
  const float*  __restrict__ ub = u + (size_t)b * MM;
  float s_l = 0.0f;
  while (w) {
    int k = (int)__builtin_ctzll(w);
    w &= w - 1;
    int m = ((k >> 1) << 7) + 2 * lane + (k & 1);
    float2 s = tl[m];
    float dx = a.x - s.x, dy = a.y - s.y;
    float t = fmaf(dy, dy, dx * dx) * kNegInvEps + ub[m];
    s_l += __expf(t);
  }
  float ssum = wave_reduce_sum(s_l);
  if (lane == 0) {
    float tot = ssum + (float)ecnt[b];   // contamination entries are exp(0)=1
    v[col] = (tot == 0.0f) ? 1.0e9f : -__logf(tot);
  }
}

// out[row,:] = sum_j attn_j * feats[n_j,:], one block per row (PROVEN 55us,
// at the 35TB/s L2 roof). Phase 1: 256 threads extract the row's bitmap
// (thread t owns the (t&3)-th 16-bit quarter of word t>>2), compute attn,
// append to LDS via atomic slot. Phase 2: 8 groups x 32 lanes gather feats.
__global__ __launch_bounds__(256) void output3_kernel(
    const float2* __restrict__ tlm, const float2* __restrict__ slm,
    const unsigned long long* __restrict__ row_bm,
    const float* __restrict__ u, const float* __restrict__ v,
    const float* __restrict__ feats, float* __restrict__ out)
{
  __shared__ float s_attn[1024];
  __shared__ unsigned short s_id[1024];
  __shared__ float4 s_red[256];
  __shared__ int s_cnt;

  const int j   = blockIdx.x;
  const int row = (j & 7) * 2048 + (j >> 3);
  const int tid = threadIdx.x;
  const int b   = row >> 12;
  if (tid == 0) s_cnt = 0;
  __syncthreads();

  {
    const int L  = tid >> 2;
    const int qp = tid & 3;
    unsigned long long w = row_bm[(size_t)row * 64 + L];
    unsigned wq = (unsigned)(unsigned short)(w >> (qp * 16));
    if (wq) {
      const float um = u[row];
      const float2 a = tlm[row];
      const float2* __restrict__ sl = slm + (size_t)b * NN;
      const float*  __restrict__ vb = v + (size_t)b * NN;
      while (wq) {
        int kk = (int)__builtin_ctz(wq);
        wq &= wq - 1;
        int k = qp * 16 + kk;
        int n = ((k >> 1) << 7) + 2 * L + (k & 1);
        float2 s = sl[n];
        float dx = a.x - s.x, dy = a.y - s.y;
        float aw = __expf(fmaf(dy, dy, dx * dx) * kNegInvEps + um + vb[n]);
        int p = atomicAdd(&s_cnt, 1);
        if (p < 1024) { s_attn[p] = aw; s_id[p] = (unsigned short)n; }
      }
    }
  }
  __syncthreads();

  int cnt = s_cnt;
  if (cnt > 1024) cnt = 1024;             // realistic max ~330, never hit
  float4* op = (float4*)(out + (size_t)row * CC);
  if (cnt == 0) {                         // covers !tgt_valid and !has_source
    if (tid < 32) op[tid] = make_float4(0.f, 0.f, 0.f, 0.f);
    return;
  }

  const int g = tid >> 5, l = tid & 31;
  const float4* __restrict__ fb = (const float4*)(feats + (size_t)b * NN * CC);
  float4 acc = make_float4(0.f, 0.f, 0.f, 0.f);
  for (int jj = g; jj < cnt; jj += 8) {
    float aw = s_attn[jj];
    int   n  = s_id[jj];
    float4 f = fb[(size_t)n * 32 + l];
    acc.x = fmaf(aw, f.x, acc.x);
    acc.y = fmaf(aw, f.y, acc.y);
    acc.z = fmaf(aw, f.z, acc.z);
    acc.w = fmaf(aw, f.w, acc.w);
  }
  s_red[tid] = acc;
  __syncthreads();
  if (tid < 32) {
    float4 r = s_red[tid];
#pragma unroll
    for (int gg = 1; gg < 8; ++gg) {
      float4 p = s_red[gg * 32 + tid];
      r.x += p.x; r.y += p.y; r.z += p.z; r.w += p.w;
    }
    op[tid] = r;
  }
}

// ---------------------------------------------------------------------------
// FALLBACK PATH (round-1 kernels, ~128 KB workspace) — used if ws too small
// ---------------------------------------------------------------------------

__global__ __launch_bounds__(256) void init_v_kernel(float* __restrict__ v) {
  int i = blockIdx.x * 256 + threadIdx.x;
  if (i < BB * NN) v[i] = 0.0f;
}

__global__ __launch_bounds__(256) void u_update_kernel(
    const float* __restrict__ src_locs, const float* __restrict__ tgt_locs,
    const int* __restrict__ src_valid, const int* __restrict__ tgt_valid,
    const float* __restrict__ v, float* __restrict__ u)
{
  const int lane = threadIdx.x & 63;
  const int row  = blockIdx.x * 4 + (threadIdx.x >> 6);
  const int b    = row / MM;
  const float tx = tgt_locs[row * 2 + 0];
  const float ty = tgt_locs[row * 2 + 1];
  const bool  tv = tgt_valid[row] != 0;
  const float2* __restrict__ sl  = (const float2*)(src_locs + (size_t)b * NN * 2);
  const float*  __restrict__ vb  = v + (size_t)b * NN;
  const int*    __restrict__ svb = src_valid + (size_t)b * NN;
  float mx = -3.0e38f;
#pragma unroll 4
  for (int i = 0; i < NN / 64; ++i) {
    int n = i * 64 + lane;
    float2 s = sl[n];
    float dx = tx - s.x, dy = ty - s.y;
    float d2 = dx * dx + dy * dy;
    bool valid = (d2 < kThresh2) & tv & (svb[n] != 0);
    float t = (valid ? d2 * kNegInvEps : kNegInf) + vb[n];
    mx = fmaxf(mx, t);
  }
  mx = wave_reduce_max(mx);
  float s = 0.0f;
#pragma unroll 4
  for (int i = 0; i < NN / 64; ++i) {
    int n = i * 64 + lane;
    float2 sc = sl[n];
    float dx = tx - sc.x, dy = ty - sc.y;
    float d2 = dx * dx + dy * dy;
    bool valid = (d2 < kThresh2) & tv & (svb[n] != 0);
    float t = (valid ? d2 * kNegInvEps : kNegInf) + vb[n];
    s += __expf(t - mx);
  }
  s = wave_reduce_sum(s);
  if (lane == 0) u[row] = -(mx + __logf(s));
}

__global__ __launch_bounds__(256) void v_update_kernel(
    const float* __restrict__ src_locs, const float* __restrict__ tgt_locs,
    const int* __restrict__ src_valid, const int* __restrict__ tgt_valid,
    const float* __restrict__ u, float* __restrict__ v)
{
  const int lane = threadIdx.x & 63;
  const int col  = blockIdx.x * 4 + (threadIdx.x >> 6);
  const int b    = col / NN;
  const float sx = src_locs[col * 2 + 0];
  const float sy = src_locs[col * 2 + 1];
  const bool  sv = src_valid[col] != 0;
  const float2* __restrict__ tl  = (const float2*)(tgt_locs + (size_t)b * MM * 2);
  const float*  __restrict__ ub  = u + (size_t)b * MM;
  const int*    __restrict__ tvb = tgt_valid + (size_t)b * MM;
  float mx = -3.0e38f;
#pragma unroll 4
  for (int i = 0; i < MM / 64; ++i) {
    int m = i * 64 + lane;
    float2 t2 = tl[m];
    float dx = t2.x - sx, dy = t2.y - sy;
    float d2 = dx * dx + dy * dy;
    bool valid = (d2 < kThresh2) & sv & (tvb[m] != 0);
    float t = (valid ? d2 * kNegInvEps : kNegInf) + ub[m];
    mx = fmaxf(mx, t);
  }
  mx = wave_reduce_max(mx);
  float s = 0.0f;
#pragma unroll 4
  for (int i = 0; i < MM / 64; ++i) {
    int m = i * 64 + lane;
    float2 t2 = tl[m];
    float dx = t2.x - sx, dy = t2.y - sy;
    float d2 = dx * dx + dy * dy;
    bool valid = (d2 < kThresh2) & sv & (tvb[m] != 0);
    float t = (valid ? d2 * kNegInvEps : kNegInf) + ub[m];
    s += __expf(t - mx);
  }
  s = wave_reduce_sum(s);
  if (lane == 0) v[col] = sv ? -(mx + __logf(s)) : 0.0f;
}

__global__ __launch_bounds__(256) void output_kernel(
    const float* __restrict__ src_locs, const float* __restrict__ tgt_locs,
    const int* __restrict__ src_valid, const int* __restrict__ tgt_valid,
    const float* __restrict__ u, const float* __restrict__ v,
    const float* __restrict__ feats, float* __restrict__ out)
{
  __shared__ float s_attn[NN];
  __shared__ int   s_idx[NN];
  __shared__ int   s_cnt;
  __shared__ float s_part[CC];
  const int row = blockIdx.x;
  const int b   = row / MM;
  const int tid = threadIdx.x;
  if (tid == 0) s_cnt = 0;
  __syncthreads();
  const float tx = tgt_locs[row * 2 + 0];
  const float ty = tgt_locs[row * 2 + 1];
  const bool  tv = tgt_valid[row] != 0;
  const float um = u[row];
  const float2* __restrict__ sl  = (const float2*)(src_locs + (size_t)b * NN * 2);
  const float*  __restrict__ vb  = v + (size_t)b * NN;
  const int*    __restrict__ svb = src_valid + (size_t)b * NN;
#pragma unroll 4
  for (int i = 0; i < NN / 256; ++i) {
    int n = i * 256 + tid;
    float2 s = sl[n];
    float dx = tx - s.x, dy = ty - s.y;
    float d2 = dx * dx + dy * dy;
    bool valid = (d2 < kThresh2) & tv & (svb[n] != 0);
    if (valid) {
      float a = __expf((d2 * kNegInvEps + um) + vb[n]);
      int p = atomicAdd(&s_cnt, 1);
      s_attn[p] = a;
      s_idx[p]  = n;
    }
  }
  __syncthreads();
  const int cnt = s_cnt;
  const int g = tid >> 7;
  const int c = tid & (CC - 1);
  const float* __restrict__ fb = feats + (size_t)b * NN * CC;
  float acc = 0.0f;
  for (int j = g; j < cnt; j += 2) {
    float a = s_attn[j];
    int   n = s_idx[j];
    acc = fmaf(a, fb[(size_t)n * CC + c], acc);
  }
  if (g == 1) s_part[c] = acc;
  __syncthreads();
  if (g == 0) {
    float r = (cnt > 0) ? (acc + s_part[c]) : 0.0f;
    out[(size_t)row * CC + c] = r;
  }
}

// ---------------------------------------------------------------------------

extern "C" void kernel_launch(void* const* d_in, const int* in_sizes, int n_in,
                              void* d_out, int out_size, void* d_ws, size_t ws_size,
                              hipStream_t stream) {
  const float* feats = (const float*)d_in[0];
  const float* sloc  = (const float*)d_in[1];
  const float* tloc  = (const float*)d_in[2];
  const int*   smask = (const int*)d_in[3];
  const int*   tmask = (const int*)d_in[4];
  float* out = (float*)d_out;

  // workspace layout (fast path): ~17 MB
  char* p = (char*)d_ws;
  float* u_   = (float*)p;            p += (size_t)BB * MM * 4;
  float* v_   = (float*)p;            p += (size_t)BB * NN * 4;
  int* ecnt   = (int*)p;              p += 256;
  float2* slm = (float2*)p;           p += (size_t)BB * NN * 8;
  float2* tlm = (float2*)p;           p += (size_t)BB * MM * 8;
  unsigned long long* row_bm = (unsigned long long*)p; p += (size_t)BB * MM * 64 * 8;
  unsigned long long* col_bm = (unsigned long long*)p; p += (size_t)BB * NN * 64 * 8;
  size_t required = (size_t)(p - (char*)d_ws);

  if (ws_size >= required) {
    prep_kernel<<<(BB * NN + 255) / 256, 256, 0, stream>>>(
        sloc, tloc, smask, tmask, v_, ecnt, slm, tlm);
    // fused sweep: row_bm + col_bm (in-block transpose) + u1 + ecnt
    sweep10_kernel<<<BB * 64, 1024, 0, stream>>>(
        slm, tlm, row_bm, col_bm, ecnt, u_);
    // u1 done; remaining chain: v1, u2, v2, u3, v3 (5 stream dispatches --
    // measured CHEAPER than any fusion: grid.sync costs ~135us/sync, R14)
    for (int it = 0; it < 3; ++it) {
      lse_col_kernel<<<BB * NN / 4, 256, 0, stream>>>(slm, tlm, col_bm,
                                                      smask, ecnt, u_, v_);
      if (it < 2)
        lse_row_kernel<<<BB * MM / 4, 256, 0, stream>>>(tlm, slm, row_bm, v_, u_);
    }
    output3_kernel<<<BB * MM, 256, 0, stream>>>(tlm, slm, row_bm,
                                                u_, v_, feats, out);
  } else {
    // fallback: round-1 path (dense re-sweeps), needs only 128 KB
    float* u = (float*)d_ws;
    float* v = u + (size_t)BB * MM;
    init_v_kernel<<<(BB * NN + 255) / 256, 256, 0, stream>>>(v);
    for (int it = 0; it < 3; ++it) {
      u_update_kernel<<<BB * MM / 4, 256, 0, stream>>>(sloc, tloc, smask, tmask, v, u);
      v_update_kernel<<<BB * NN / 4, 256, 0, stream>>>(sloc, tloc, smask, tmask, u, v);
    }
    output_kernel<<<BB * MM, 256, 0, stream>>>(sloc, tloc, smask, tmask, u, v, feats, out);
  }
}

// Round 13
// 223.342 us; speedup vs baseline: 3.7635x; 1.0380x over previous
//
#include <hip/hip_runtime.h>

// GeometryOptimalTransport: B=4, N=M=4096, C=128
// Sinkhorn (3 iters) over log_K(m,n) = -dist2/eps masked to -1e9, then
// attn-weighted gather of source feats.
//
// R2: validity is iteration-invariant -> precompute adjacency once; run all
// lse updates + output on the ~3% dense structure. Finite NEG_INF=-1e9
// contamination is closed-form:
//   - row with 0 valid entries => u = +1e9 EXACTLY (ulp(1e9)=64)
//   - such rows contribute exp(0) to EVERY column lse => per-batch count cc
//   - all other invalid entries underflow to exactly 0 in fp32.
// Journal of falsified theories (keep for future sessions):
//   - compaction in ANY form costs ~60us (R5/R6) -> permuted bitmap instead
//     (bit k of lane L's word <=> partner n=(k>>1)*128+2L+(k&1))
//   - sweep ~70us: invariant to load volume (R5), LDS staging (R8),
//     compaction removal (R7), block count (R9), fused exp work (R11).
//   - sorted 4-row output REGRESSED (R12): gather set 118KB >> 32KB L1.
//   - 128-thr lse split NEUTRAL (R13): divergent tail was not the gate.
//   - cooperative grid.sync costs ~135us PER SYNC on MI355X (R14) ->
//     stream dispatch boundaries are the CHEAP phase-ordering. NEVER coop.
// R15: best composition = prep + sweep10 (fused sweep+u1+transpose, 72us)
// + 5-dispatch lse chain (~20us each) + output3 (55us, at 35TB/s L2 roof)
// = 232us.
// R16 (this round): every sparse kernel stalls at 25-35% VALUBusy; bottom-up
// arithmetic says the per-CU scattered-line path (~1 line/cy) is the gate:
// each pair-entry issues TWO scattered loads (locs 8B + dual 4B, 2 lines).
// Fix: pack (loc.x, loc.y, dual) into one float4, maintained by the
// producer that already has both in registers (prep/sweep10/lse passes) ->
// ONE 16B scattered load per pair. Predicted: lse 20 -> 13-16us each,
// output3 -5us, total ~200-212us.

constexpr int   BB = 4;
constexpr int   NN = 4096;
constexpr int   MM = 4096;
constexpr int   CC = 128;
constexpr float kNegInf    = -1000000000.0f;
constexpr float kThresh2   = 0.04f;                 // 0.2^2
constexpr float kNegInvEps = -(1.0f / 0.01000001f); // -(1/(EPSILON+1e-8))

__device__ inline float wave_reduce_sum(float x) {
#pragma unroll
  for (int off = 32; off > 0; off >>= 1)
    x += __shfl_xor(x, off, 64);
  return x;
}
__device__ inline float wave_reduce_max(float x) {
#pragma unroll
  for (int off = 32; off > 0; off >>= 1)
    x = fmaxf(x, __shfl_xor(x, off, 64));
  return x;
}

// ---------------------------------------------------------------------------
// FAST PATH (needs ~18 MB workspace)
// ---------------------------------------------------------------------------

// zero v, fold masks into locs (invalid -> far sentinel; DIFFERENT sentinels
// per side so two invalid points are never "close"); init packed source
// (sx, sy, v=0).
__global__ __launch_bounds__(256) void prep_kernel(
    const float* __restrict__ sloc, const float* __restrict__ tloc,
    const int* __restrict__ sm, const int* __restrict__ tm,
    float* __restrict__ v, int* __restrict__ ecnt,
    float2* __restrict__ slm, float2* __restrict__ tlm,
    float4* __restrict__ pk_s)
{
  int i = blockIdx.x * 256 + threadIdx.x;
  if (i < BB * NN) {
    v[i] = 0.0f;
    float2 s = ((const float2*)sloc)[i];
    float2 sv = sm[i] ? s : make_float2(1.0e9f, 1.0e9f);
    slm[i] = sv;
    pk_s[i] = make_float4(sv.x, sv.y, 0.0f, 0.0f);
    float2 t = ((const float2*)tloc)[i];
    tlm[i] = tm[i] ? t : make_float2(3.0e9f, 3.0e9f);
    if (i < BB) ecnt[i] = 0;
  }
}

// Fused sweep + u1 + bit-transpose. One block per (batch b, L'): 1024 thr =
// 16 waves, wave wid owns rows m = {base, base+1, base+128, base+129},
// base = wid*256 + 2L'. Lane L, iter i tests partners i*128+2L, i*128+2L+1;
// bit k of lane L's word <=> n=(k>>1)*128+2L+(k&1). After the sweep: row_bm
// + u1 (v0=0) + packed target (tx,ty,u1) + ecnt census, then the block
// stages its 64x64 word tile in LDS (rotated slots) and each wave
// butterfly-transposes 4 column tiles.
__global__ __launch_bounds__(1024) void sweep10_kernel(
    const float2* __restrict__ slm, const float2* __restrict__ tlm,
    unsigned long long* __restrict__ row_bm,
    unsigned long long* __restrict__ col_bm,
    int* __restrict__ ecnt, float* __restrict__ u,
    float4* __restrict__ pk_t)
{
  __shared__ unsigned long long tile[64 * 64];   // 32 KB

  const int b    = blockIdx.x >> 6;
  const int Lp   = blockIdx.x & 63;              // L'
  const int tid  = threadIdx.x;
  const int lane = tid & 63;
  const int wid  = tid >> 6;                     // 0..15
  const int base = b * 4096 + wid * 256 + 2 * Lp;
  const int m0 = base, m1 = base + 1, m2 = base + 128, m3 = base + 129;

  const float2 a0 = tlm[m0];
  const float2 a1 = tlm[m1];
  const float2 a2 = tlm[m2];
  const float2 a3 = tlm[m3];
  const float4* __restrict__ bl4 = (const float4*)(slm + (size_t)b * 4096);

  unsigned long long w0 = 0, w1 = 0, w2 = 0, w3 = 0;
  float s0 = 0.0f, s1 = 0.0f, s2 = 0.0f, s3 = 0.0f;
#pragma unroll 8
  for (int i = 0; i < 32; ++i) {
    float4 q = bl4[i * 64 + lane];
#define SWTEST(aa, ww, ss)                                         \
    do {                                                           \
      float dx0 = (aa).x - q.x, dy0 = (aa).y - q.y;                \
      float dx1 = (aa).x - q.z, dy1 = (aa).y - q.w;                \
      float d0 = fmaf(dy0, dy0, dx0 * dx0);                        \
      float d1 = fmaf(dy1, dy1, dx1 * dx1);                        \
      bool p0 = d0 < kThresh2;                                     \
      bool p1 = d1 < kThresh2;                                     \
      ww = (ww >> 2) | (p0 ? (1ull << 62) : 0ull)                  \
                     | (p1 ? (1ull << 63) : 0ull);                 \
      float e0 = __expf(d0 * kNegInvEps);                          \
      float e1 = __expf(d1 * kNegInvEps);                          \
      ss += p0 ? e0 : 0.0f;                                        \
      ss += p1 ? e1 : 0.0f;                                        \
    } while (0)
    SWTEST(a0, w0, s0);
    SWTEST(a1, w1, s1);
    SWTEST(a2, w2, s2);
    SWTEST(a3, w3, s3);
#undef SWTEST
  }

  row_bm[(size_t)m0 * 64 + lane] = w0;
  row_bm[(size_t)m1 * 64 + lane] = w1;
  row_bm[(size_t)m2 * 64 + lane] = w2;
  row_bm[(size_t)m3 * 64 + lane] = w3;

  // stage tile rows (rho = wid*4 + j), rotated slot (lane+rho)&63
  {
    const int r0 = wid * 4;
    tile[(r0 + 0) * 64 + ((lane + r0 + 0) & 63)] = w0;
    tile[(r0 + 1) * 64 + ((lane + r0 + 1) & 63)] = w1;
    tile[(r0 + 2) * 64 + ((lane + r0 + 2) & 63)] = w2;
    tile[(r0 + 3) * 64 + ((lane + r0 + 3) & 63)] = w3;
  }

  // u1 = -log(ssum) per row (v0 = 0); ssum==0 <=> empty row (valid terms
  // are exp(t), t >= -4, so a non-empty row's sum cannot underflow).
  s0 = wave_reduce_sum(s0);
  s1 = wave_reduce_sum(s1);
  s2 = wave_reduce_sum(s2);
  s3 = wave_reduce_sum(s3);
  if (lane == 0) {
    float u0 = (s0 == 0.0f) ? 1.0e9f : -__logf(s0);
    float u1v = (s1 == 0.0f) ? 1.0e9f : -__logf(s1);
    float u2v = (s2 == 0.0f) ? 1.0e9f : -__logf(s2);
    float u3v = (s3 == 0.0f) ? 1.0e9f : -__logf(s3);
    u[m0] = u0; u[m1] = u1v; u[m2] = u2v; u[m3] = u3v;
    pk_t[m0] = make_float4(a0.x, a0.y, u0, 0.0f);
    pk_t[m1] = make_float4(a1.x, a1.y, u1v, 0.0f);
    pk_t[m2] = make_float4(a2.x, a2.y, u2v, 0.0f);
    pk_t[m3] = make_float4(a3.x, a3.y, u3v, 0.0f);
    int e = (s0 == 0.0f) + (s1 == 0.0f) + (s2 == 0.0f) + (s3 == 0.0f);
    if (e) atomicAdd(&ecnt[b], e);
  }
  __syncthreads();

  // transpose: wave wid handles Lt = wid*4..+3 (verified butterfly from R9)
  unsigned long long* __restrict__ cb = col_bm + ((size_t)b << 12) * 64;
#pragma unroll
  for (int i = 0; i < 4; ++i) {
    const int Lt = wid * 4 + i;
    unsigned long long w = tile[lane * 64 + ((Lt + lane) & 63)];
#define BTSTEP(S, MLO)                                                  \
    do {                                                                \
      unsigned long long t = __shfl_xor(w, S, 64);                      \
      w = (lane & S) ? ((w & ~(MLO)) | ((t >> S) & (MLO)))              \
                     : ((w & (MLO)) | ((t & (MLO)) << S));              \
    } while (0)
    BTSTEP(32, 0x00000000FFFFFFFFull);
    BTSTEP(16, 0x0000FFFF0000FFFFull);
    BTSTEP(8,  0x00FF00FF00FF00FFull);
    BTSTEP(4,  0x0F0F0F0F0F0F0F0Full);
    BTSTEP(2,  0x3333333333333333ull);
    BTSTEP(1,  0x5555555555555555ull);
#undef BTSTEP
    const int n = ((lane >> 1) << 7) + 2 * Lt + (lane & 1);
    cb[(size_t)n * 64 + Lp] = w;
  }
}

// u[row] = -log(sum_j exp(logK_j + v[n_j])), +1e9 if no valid entries.
// One wave per row. Lane L ctz-enumerates its own bitmap word; ONE packed
// 16B load (sx,sy,v) per entry. No max pass: |t| << 87. Producer-side:
// writes pk_t = (tx,ty,u) for the next col pass.
__global__ __launch_bounds__(256) void lse_row_kernel(
    const float2* __restrict__ tlm,
    const float4* __restrict__ pk_s,
    const unsigned long long* __restrict__ row_bm,
    float* __restrict__ u, float4* __restrict__ pk_t)
{
  const int lane = threadIdx.x & 63;
  const int j    = blockIdx.x;
  const int row  = (j & 7) * 2048 + (j >> 3) * 4 + (threadIdx.x >> 6);
  const int b    = row >> 12;
  unsigned long long w = row_bm[(size_t)row * 64 + lane];
  const float2 a = tlm[row];
  const float4* __restrict__ ps = pk_s + (size_t)b * NN;
  float s_l = 0.0f;
  while (w) {
    int k = (int)__builtin_ctzll(w);
    w &= w - 1;
    int n = ((k >> 1) << 7) + 2 * lane + (k & 1);
    float4 p = ps[n];
    float dx = a.x - p.x, dy = a.y - p.y;
    float t = fmaf(dy, dy, dx * dx) * kNegInvEps + p.z;
    s_l += __expf(t);
  }
  float ssum = wave_reduce_sum(s_l);
  if (lane == 0) {
    float uv = (ssum == 0.0f) ? 1.0e9f : -__logf(ssum);
    u[row] = uv;
    pk_t[row] = make_float4(a.x, a.y, uv, 0.0f);
  }
}

// v[col] = !sv ? 0 : -log(sum exp(t) + cc); +1e9 if both empty.
// One packed 16B load (tx,ty,u) per entry. Writes pk_s = (sx,sy,v) for the
// next row pass / output.
__global__ __launch_bounds__(256) void lse_col_kernel(
    const float2* __restrict__ slm,
    const float4* __restrict__ pk_t,
    const unsigned long long* __restrict__ col_bm,
    const int* __restrict__ smask, const int* __restrict__ ecnt,
    float* __restrict__ v, float4* __restrict__ pk_s)
{
  const int lane = threadIdx.x & 63;
  const int j    = blockIdx.x;
  const int col  = (j & 7) * 2048 + (j >> 3) * 4 + (threadIdx.x >> 6);
  if (!smask[col]) {
    if (lane == 0) {
      v[col] = 0.0f;
      pk_s[col] = make_float4(1.0e9f, 1.0e9f, 0.0f, 0.0f);  // sentinel; never
    }                                                        // read via bitmap
    return;
  }
  const int b = col >> 12;
  unsigned long long w = col_bm[(size_t)col * 64 + lane];
  const float2 a = slm[col];
  const float4* __restrict__ pt = pk_t + (size_t)b * MM;
  float s_l = 0.0f;
  while (w) {
    int k = (int)__builtin_ctzll(w);
    w &= w - 1;
    int m = ((k >> 1) << 7) + 2 * lane + (k & 1);
    float4 p = pt[m];
    float dx = a.x - p.x, dy = a.y - p.y;
    float t = fmaf(dy, dy, dx * dx) * kNegInvEps + p.z;
    s_l += __expf(t);
  }
  float ssum = wave_reduce_sum(s_l);
  if (lane == 0) {
    float tot = ssum + (float)ecnt[b];   // contamination entries are exp(0)=1
    float vv = (tot == 0.0f) ? 1.0e9f : -__logf(tot);
    v[col] = vv;
    pk_s[col] = make_float4(a.x, a.y, vv, 0.0f);
  }
}

// out[row,:] = sum_j attn_j * feats[n_j,:], one block per row (at the
// 35TB/s L2 roof). Phase 1: 256 threads extract the row's bitmap (thread t
// owns the (t&3)-th 16-bit quarter of word t>>2), ONE packed 16B load per
// pair (sx,sy,v3), compute attn, append to LDS via atomic slot. Phase 2:
// 8 groups x 32 lanes gather feats float4 and reduce.
__global__ __launch_bounds__(256) void output3_kernel(
    const float2* __restrict__ tlm,
    const float4* __restrict__ pk_s,
    const unsigned long long* __restrict__ row_bm,
    const float* __restrict__ u,
    const float* __restrict__ feats, float* __restrict__ out)
{
  __shared__ float s_attn[1024];
  __shared__ unsigned short s_id[1024];
  __shared__ float4 s_red[256];
  __shared__ int s_cnt;

  const int j   = blockIdx.x;
  const int row = (j & 7) * 2048 + (j >> 3);
  const int tid = threadIdx.x;
  const int b   = row >> 12;
  if (tid == 0) s_cnt = 0;
  __syncthreads();

  {
    const int L  = tid >> 2;
    const int qp = tid & 3;
    unsigned long long w = row_bm[(size_t)row * 64 + L];
    unsigned wq = (unsigned)(unsigned short)(w >> (qp * 16));
    if (wq) {
      const float um = u[row];
      const float2 a = tlm[row];
      const float4* __restrict__ ps = pk_s + (size_t)b * NN;
      while (wq) {
        int kk = (int)__builtin_ctz(wq);
        wq &= wq - 1;
        int k = qp * 16 + kk;
        int n = ((k >> 1) << 7) + 2 * L + (k & 1);
        float4 p = ps[n];
        float dx = a.x - p.x, dy = a.y - p.y;
        float aw = __expf(fmaf(dy, dy, dx * dx) * kNegInvEps + um + p.z);
        int pos = atomicAdd(&s_cnt, 1);
        if (pos < 1024) { s_attn[pos] = aw; s_id[pos] = (unsigned short)n; }
      }
    }
  }
  __syncthreads();

  int cnt = s_cnt;
  if (cnt > 1024) cnt = 1024;             // realistic max ~330, never hit
  float4* op = (float4*)(out + (size_t)row * CC);
  if (cnt == 0) {                         // covers !tgt_valid and !has_source
    if (tid < 32) op[tid] = make_float4(0.f, 0.f, 0.f, 0.f);
    return;
  }

  const int g = tid >> 5, l = tid & 31;
  const float4* __restrict__ fb = (const float4*)(feats + (size_t)b * NN * CC);
  float4 acc = make_float4(0.f, 0.f, 0.f, 0.f);
  for (int jj = g; jj < cnt; jj += 8) {
    float aw = s_attn[jj];
    int   n  = s_id[jj];
    float4 f = fb[(size_t)n * 32 + l];
    acc.x = fmaf(aw, f.x, acc.x);
    acc.y = fmaf(aw, f.y, acc.y);
    acc.z = fmaf(aw, f.z, acc.z);
    acc.w = fmaf(aw, f.w, acc.w);
  }
  s_red[tid] = acc;
  __syncthreads();
  if (tid < 32) {
    float4 r = s_red[tid];
#pragma unroll
    for (int gg = 1; gg < 8; ++gg) {
      float4 p = s_red[gg * 32 + tid];
      r.x += p.x; r.y += p.y; r.z += p.z; r.w += p.w;
    }
    op[tid] = r;
  }
}

// ---------------------------------------------------------------------------
// FALLBACK PATH (round-1 kernels, ~128 KB workspace) — used if ws too small
// ---------------------------------------------------------------------------

__global__ __launch_bounds__(256) void init_v_kernel(float* __restrict__ v) {
  int i = blockIdx.x * 256 + threadIdx.x;
  if (i < BB * NN) v[i] = 0.0f;
}

__global__ __launch_bounds__(256) void u_update_kernel(
    const float* __restrict__ src_locs, const float* __restrict__ tgt_locs,
    const int* __restrict__ src_valid, const int* __restrict__ tgt_valid,
    const float* __restrict__ v, float* __restrict__ u)
{
  const int lane = threadIdx.x & 63;
  const int row  = blockIdx.x * 4 + (threadIdx.x >> 6);
  const int b    = row / MM;
  const float tx = tgt_locs[row * 2 + 0];
  const float ty = tgt_locs[row * 2 + 1];
  const bool  tv = tgt_valid[row] != 0;
  const float2* __restrict__ sl  = (const float2*)(src_locs + (size_t)b * NN * 2);
  const float*  __restrict__ vb  = v + (size_t)b * NN;
  const int*    __restrict__ svb = src_valid + (size_t)b * NN;
  float mx = -3.0e38f;
#pragma unroll 4
  for (int i = 0; i < NN / 64; ++i) {
    int n = i * 64 + lane;
    float2 s = sl[n];
    float dx = tx - s.x, dy = ty - s.y;
    float d2 = dx * dx + dy * dy;
    bool valid = (d2 < kThresh2) & tv & (svb[n] != 0);
    float t = (valid ? d2 * kNegInvEps : kNegInf) + vb[n];
    mx = fmaxf(mx, t);
  }
  mx = wave_reduce_max(mx);
  float s = 0.0f;
#pragma unroll 4
  for (int i = 0; i < NN / 64; ++i) {
    int n = i * 64 + lane;
    float2 sc = sl[n];
    float dx = tx - sc.x, dy = ty - sc.y;
    float d2 = dx * dx + dy * dy;
    bool valid = (d2 < kThresh2) & tv & (svb[n] != 0);
    float t = (valid ? d2 * kNegInvEps : kNegInf) + vb[n];
    s += __expf(t - mx);
  }
  s = wave_reduce_sum(s);
  if (lane == 0) u[row] = -(mx + __logf(s));
}

__global__ __launch_bounds__(256) void v_update_kernel(
    const float* __restrict__ src_locs, const float* __restrict__ tgt_locs,
    const int* __restrict__ src_valid, const int* __restrict__ tgt_valid,
    const float* __restrict__ u, float* __restrict__ v)
{
  const int lane = threadIdx.x & 63;
  const int col  = blockIdx.x * 4 + (threadIdx.x >> 6);
  const int b    = col / NN;
  const float sx = src_locs[col * 2 + 0];
  const float sy = src_locs[col * 2 + 1];
  const bool  sv = src_valid[col] != 0;
  const float2* __restrict__ tl  = (const float2*)(tgt_locs + (size_t)b * MM * 2);
  const float*  __restrict__ ub  = u + (size_t)b * MM;
  const int*    __restrict__ tvb = tgt_valid + (size_t)b * MM;
  float mx = -3.0e38f;
#pragma unroll 4
  for (int i = 0; i < MM / 64; ++i) {
    int m = i * 64 + lane;
    float2 t2 = tl[m];
    float dx = t2.x - sx, dy = t2.y - sy;
    float d2 = dx * dx + dy * dy;
    bool valid = (d2 < kThresh2) & sv & (tvb[m] != 0);
    float t = (valid ? d2 * kNegInvEps : kNegInf) + ub[m];
    mx = fmaxf(mx, t);
  }
  mx = wave_reduce_max(mx);
  float s = 0.0f;
#pragma unroll 4
  for (int i = 0; i < MM / 64; ++i) {
    int m = i * 64 + lane;
    float2 t2 = tl[m];
    float dx = t2.x - sx, dy = t2.y - sy;
    float d2 = dx * dx + dy * dy;
    bool valid = (d2 < kThresh2) & sv & (tvb[m] != 0);
    float t = (valid ? d2 * kNegInvEps : kNegInf) + ub[m];
    s += __expf(t - mx);
  }
  s = wave_reduce_sum(s);
  if (lane == 0) v[col] = sv ? -(mx + __logf(s)) : 0.0f;
}

__global__ __launch_bounds__(256) void output_kernel(
    const float* __restrict__ src_locs, const float* __restrict__ tgt_locs,
    const int* __restrict__ src_valid, const int* __restrict__ tgt_valid,
    const float* __restrict__ u, const float* __restrict__ v,
    const float* __restrict__ feats, float* __restrict__ out)
{
  __shared__ float s_attn[NN];
  __shared__ int   s_idx[NN];
  __shared__ int   s_cnt;
  __shared__ float s_part[CC];
  const int row = blockIdx.x;
  const int b   = row / MM;
  const int tid = threadIdx.x;
  if (tid == 0) s_cnt = 0;
  __syncthreads();
  const float tx = tgt_locs[row * 2 + 0];
  const float ty = tgt_locs[row * 2 + 1];
  const bool  tv = tgt_valid[row] != 0;
  const float um = u[row];
  const float2* __restrict__ sl  = (const float2*)(src_locs + (size_t)b * NN * 2);
  const float*  __restrict__ vb  = v + (size_t)b * NN;
  const int*    __restrict__ svb = src_valid + (size_t)b * NN;
#pragma unroll 4
  for (int i = 0; i < NN / 256; ++i) {
    int n = i * 256 + tid;
    float2 s = sl[n];
    float dx = tx - s.x, dy = ty - s.y;
    float d2 = dx * dx + dy * dy;
    bool valid = (d2 < kThresh2) & tv & (svb[n] != 0);
    if (valid) {
      float a = __expf((d2 * kNegInvEps + um) + vb[n]);
      int p = atomicAdd(&s_cnt, 1);
      s_attn[p] = a;
      s_idx[p]  = n;
    }
  }
  __syncthreads();
  const int cnt = s_cnt;
  const int g = tid >> 7;
  const int c = tid & (CC - 1);
  const float* __restrict__ fb = feats + (size_t)b * NN * CC;
  float acc = 0.0f;
  for (int j = g; j < cnt; j += 2) {
    float a = s_attn[j];
    int   n = s_idx[j];
    acc = fmaf(a, fb[(size_t)n * CC + c], acc);
  }
  if (g == 1) s_part[c] = acc;
  __syncthreads();
  if (g == 0) {
    float r = (cnt > 0) ? (acc + s_part[c]) : 0.0f;
    out[(size_t)row * CC + c] = r;
  }
}

// ---------------------------------------------------------------------------

extern "C" void kernel_launch(void* const* d_in, const int* in_sizes, int n_in,
                              void* d_out, int out_size, void* d_ws, size_t ws_size,
                              hipStream_t stream) {
  const float* feats = (const float*)d_in[0];
  const float* sloc  = (const float*)d_in[1];
  const float* tloc  = (const float*)d_in[2];
  const int*   smask = (const int*)d_in[3];
  const int*   tmask = (const int*)d_in[4];
  float* out = (float*)d_out;

  // workspace layout (fast path): ~18 MB
  char* p = (char*)d_ws;
  float* u_   = (float*)p;            p += (size_t)BB * MM * 4;
  float* v_   = (float*)p;            p += (size_t)BB * NN * 4;
  int* ecnt   = (int*)p;              p += 256;
  float2* slm = (float2*)p;           p += (size_t)BB * NN * 8;
  float2* tlm = (float2*)p;           p += (size_t)BB * MM * 8;
  float4* pk_s = (float4*)p;          p += (size_t)BB * NN * 16;
  float4* pk_t = (float4*)p;          p += (size_t)BB * MM * 16;
  unsigned long long* row_bm = (unsigned long long*)p; p += (size_t)BB * MM * 64 * 8;
  unsigned long long* col_bm = (unsigned long long*)p; p += (size_t)BB * NN * 64 * 8;
  size_t required = (size_t)(p - (char*)d_ws);

  if (ws_size >= required) {
    prep_kernel<<<(BB * NN + 255) / 256, 256, 0, stream>>>(
        sloc, tloc, smask, tmask, v_, ecnt, slm, tlm, pk_s);
    // fused sweep: row_bm + col_bm (in-block transpose) + u1 + pk_t + ecnt
    sweep10_kernel<<<BB * 64, 1024, 0, stream>>>(
        slm, tlm, row_bm, col_bm, ecnt, u_, pk_t);
    // u1 done; remaining chain: v1, u2, v2, u3, v3 (5 stream dispatches --
    // measured CHEAPER than any fusion: grid.sync costs ~135us/sync, R14)
    for (int it = 0; it < 3; ++it) {
      lse_col_kernel<<<BB * NN / 4, 256, 0, stream>>>(slm, pk_t, col_bm,
                                                      smask, ecnt, v_, pk_s);
      if (it < 2)
        lse_row_kernel<<<BB * MM / 4, 256, 0, stream>>>(tlm, pk_s, row_bm,
                                                        u_, pk_t);
    }
    output3_kernel<<<BB * MM, 256, 0, stream>>>(tlm, pk_s, row_bm,
                                                u_, feats, out);
  } else {
    // fallback: round-1 path (dense re-sweeps), needs only 128 KB
    float* u = (float*)d_ws;
    float* v = u + (size_t)BB * MM;
    init_v_kernel<<<(BB * NN + 255) / 256, 256, 0, stream>>>(v);
    for (int it = 0; it < 3; ++it) {
      u_update_kernel<<<BB * MM / 4, 256, 0, stream>>>(sloc, tloc, smask, tmask, v, u);
      v_update_kernel<<<BB * NN / 4, 256, 0, stream>>>(sloc, tloc, smask, tmask, u, v);
    }
    output_kernel<<<BB * MM, 256, 0, stream>>>(sloc, tloc, smask, tmask, u, v, feats, out);
  }
}

// Round 15
// 189.441 us; speedup vs baseline: 4.4369x; 1.1790x over previous
//
#include <hip/hip_runtime.h>

// GeometryOptimalTransport: B=4, N=M=4096, C=128
// Sinkhorn (3 iters) over log_K(m,n) = -dist2/eps masked to -1e9, then
// attn-weighted gather of source feats.
//
// R2: validity is iteration-invariant -> precompute adjacency once; run all
// lse updates + output on the ~3% dense structure. Finite NEG_INF=-1e9
// contamination is closed-form:
//   - row with 0 valid entries => u = +1e9 EXACTLY (ulp(1e9)=64)
//   - such rows contribute exp(0) to EVERY column lse => per-batch count cc
//   - all other invalid entries underflow to exactly 0 in fp32.
// Journal of falsified theories (keep for future sessions):
//   - compaction in ANY form costs ~60us (R5/R6) -> permuted bitmap instead
//     (bit k of lane L's word <=> partner n=(k>>1)*128+2L+(k&1))
//   - sorted 4-row output REGRESSED (R12): gather set 118KB >> 32KB L1.
//   - 128-thr lse split NEUTRAL (R13): divergent tail was not the gate.
//   - cooperative grid.sync costs ~135us PER SYNC on MI355X (R14). NEVER.
//   - scattered-LINE count only a minor factor (R16: 2x fewer lines -> -8.5us
//     not -30): packed float4 (x,y,dual) kept (it did help).
// R17 insight: sweep6 (8 waves/SIMD, BOTH sides) = 61us vs sweep10
// (4 waves/SIMD, one side) = 72us -> ~2.4x per-test throughput from 2x TLP.
// All sweep "stall" ablations held TLP constant; occupancy was 16-40%
// everywhere. The stall is ordinary latency-hiding shortfall.
// R17: (a) sweep11 = sweep10 split into 2 half-partner blocks (h=0/1,
// 16 iters each) -> 512 blocks, 2/CU, 8 waves/SIMD. Row bitmaps as
// non-overlapping u32 halves; butterfly per-half (output lanes kap in
// [32h,32h+32) carry complete col words, written once); u1 via atomicAdd
// partials into S + tiny u1fin kernel (u1, pk_t, ecnt census).
// (b) 2-way software-pipelined lse enumeration (2 loads in flight).
// R18: R17 bench hit the recurring infra failure ("container failed twice",
// 3rd occurrence; R5/R9 both resolved on unchanged resubmission). Kernel
// re-audited (half-split algebra, butterfly coverage, dataflow, barriers)
// and resubmitted unchanged.

constexpr int   BB = 4;
constexpr int   NN = 4096;
constexpr int   MM = 4096;
constexpr int   CC = 128;
constexpr float kNegInf    = -1000000000.0f;
constexpr float kThresh2   = 0.04f;                 // 0.2^2
constexpr float kNegInvEps = -(1.0f / 0.01000001f); // -(1/(EPSILON+1e-8))

__device__ inline float wave_reduce_sum(float x) {
#pragma unroll
  for (int off = 32; off > 0; off >>= 1)
    x += __shfl_xor(x, off, 64);
  return x;
}
__device__ inline float wave_reduce_max(float x) {
#pragma unroll
  for (int off = 32; off > 0; off >>= 1)
    x = fmaxf(x, __shfl_xor(x, off, 64));
  return x;
}

// ---------------------------------------------------------------------------
// FAST PATH (needs ~18 MB workspace)
// ---------------------------------------------------------------------------

// zero u1-partials S + ecnt, fold masks into locs (invalid -> far sentinel;
// DIFFERENT sentinels per side so two invalid points are never "close");
// init packed source (sx, sy, v=0).
__global__ __launch_bounds__(256) void prep_kernel(
    const float* __restrict__ sloc, const float* __restrict__ tloc,
    const int* __restrict__ sm, const int* __restrict__ tm,
    float* __restrict__ S, int* __restrict__ ecnt,
    float2* __restrict__ slm, float2* __restrict__ tlm,
    float4* __restrict__ pk_s)
{
  int i = blockIdx.x * 256 + threadIdx.x;
  if (i < BB * NN) {
    S[i] = 0.0f;
    float2 s = ((const float2*)sloc)[i];
    float2 sv = sm[i] ? s : make_float2(1.0e9f, 1.0e9f);
    slm[i] = sv;
    pk_s[i] = make_float4(sv.x, sv.y, 0.0f, 0.0f);
    float2 t = ((const float2*)tloc)[i];
    tlm[i] = tm[i] ? t : make_float2(3.0e9f, 3.0e9f);
    if (i < BB) ecnt[i] = 0;
  }
}

// Split sweep + u1-partials + bit-transpose. One block per (b, L', h):
// 512 blocks (2/CU -> 8 waves/SIMD), 1024 thr = 16 waves, wave wid owns
// rows {base, base+1, base+128, base+129}, base = wid*256 + 2L'.
// Half h tests partners [h*2048, (h+1)*2048) in 16 iters; mask bits land in
// the h-th u32 of the row word (bit k=32h+2*ii+p <=> n=(16h+ii)*128+2L+p).
// Row halves stored as u32 (non-overlapping). u1 partial sums atomicAdd
// into S[row]. Butterfly runs on the shifted half-word tile; output lanes
// kap in [32h, 32h+32) hold COMPLETE col words (all 64 row bits present in
// this block) and are written exactly once across the two h-blocks.
__global__ __launch_bounds__(1024) void sweep11_kernel(
    const float2* __restrict__ slm, const float2* __restrict__ tlm,
    unsigned long long* __restrict__ row_bm,
    unsigned long long* __restrict__ col_bm,
    float* __restrict__ S)
{
  __shared__ unsigned long long tile[64 * 64];   // 32 KB

  const int blk  = blockIdx.x;
  const int b    = blk >> 7;
  const int Lp   = (blk >> 1) & 63;              // L'
  const int h    = blk & 1;
  const int tid  = threadIdx.x;
  const int lane = tid & 63;
  const int wid  = tid >> 6;                     // 0..15
  const int base = b * 4096 + wid * 256 + 2 * Lp;
  const int ra = base, rb = base + 1, rc = base + 128, rd = base + 129;

  const float2 a0 = tlm[ra];
  const float2 a1 = tlm[rb];
  const float2 a2 = tlm[rc];
  const float2 a3 = tlm[rd];
  const float4* __restrict__ bl4 =
      (const float4*)(slm + (size_t)b * 4096) + (size_t)h * 16 * 64;

  unsigned m0 = 0, m1 = 0, m2 = 0, m3 = 0;
  float s0 = 0.0f, s1 = 0.0f, s2 = 0.0f, s3 = 0.0f;
#pragma unroll 8
  for (int ii = 0; ii < 16; ++ii) {
    float4 q = bl4[ii * 64 + lane];
#define SWTEST(aa, mm, ss)                                         \
    do {                                                           \
      float dx0 = (aa).x - q.x, dy0 = (aa).y - q.y;                \
      float dx1 = (aa).x - q.z, dy1 = (aa).y - q.w;                \
      float d0 = fmaf(dy0, dy0, dx0 * dx0);                        \
      float d1 = fmaf(dy1, dy1, dx1 * dx1);                        \
      bool p0 = d0 < kThresh2;                                     \
      bool p1 = d1 < kThresh2;                                     \
      mm = (mm >> 2) | (p0 ? (1u << 30) : 0u)                      \
                     | (p1 ? (1u << 31) : 0u);                     \
      float e0 = __expf(d0 * kNegInvEps);                          \
      float e1 = __expf(d1 * kNegInvEps);                          \
      ss += p0 ? e0 : 0.0f;                                        \
      ss += p1 ? e1 : 0.0f;                                        \
    } while (0)
    SWTEST(a0, m0, s0);
    SWTEST(a1, m1, s1);
    SWTEST(a2, m2, s2);
    SWTEST(a3, m3, s3);
#undef SWTEST
  }

  // row halves: u32 at word offset h (little-endian: h=0 -> bits 0..31)
  unsigned* __restrict__ rb32 = (unsigned*)row_bm;
  rb32[((size_t)ra * 64 + lane) * 2 + h] = m0;
  rb32[((size_t)rb * 64 + lane) * 2 + h] = m1;
  rb32[((size_t)rc * 64 + lane) * 2 + h] = m2;
  rb32[((size_t)rd * 64 + lane) * 2 + h] = m3;

  const int sh = 32 * h;
  const unsigned long long w0 = (unsigned long long)m0 << sh;
  const unsigned long long w1 = (unsigned long long)m1 << sh;
  const unsigned long long w2 = (unsigned long long)m2 << sh;
  const unsigned long long w3 = (unsigned long long)m3 << sh;

  // stage tile rows (rho = wid*4 + j), rotated slot (lane+rho)&63
  {
    const int r0 = wid * 4;
    tile[(r0 + 0) * 64 + ((lane + r0 + 0) & 63)] = w0;
    tile[(r0 + 1) * 64 + ((lane + r0 + 1) & 63)] = w1;
    tile[(r0 + 2) * 64 + ((lane + r0 + 2) & 63)] = w2;
    tile[(r0 + 3) * 64 + ((lane + r0 + 3) & 63)] = w3;
  }

  // u1 partial sums (both halves add; finalize kernel takes -log)
  s0 = wave_reduce_sum(s0);
  s1 = wave_reduce_sum(s1);
  s2 = wave_reduce_sum(s2);
  s3 = wave_reduce_sum(s3);
  if (lane == 0) {
    if (s0 != 0.0f) atomicAdd(&S[ra], s0);
    if (s1 != 0.0f) atomicAdd(&S[rb], s1);
    if (s2 != 0.0f) atomicAdd(&S[rc], s2);
    if (s3 != 0.0f) atomicAdd(&S[rd], s3);
  }
  __syncthreads();

  // transpose: wave wid handles Lt = wid*4..+3 (verified butterfly from R9).
  // Only output lanes kap with (kap>>5)==h carry this half's (complete)
  // col words; each col word is written by exactly one h-block.
  unsigned long long* __restrict__ cb = col_bm + ((size_t)b << 12) * 64;
#pragma unroll
  for (int i = 0; i < 4; ++i) {
    const int Lt = wid * 4 + i;
    unsigned long long w = tile[lane * 64 + ((Lt + lane) & 63)];
#define BTSTEP(SS, MLO)                                                 \
    do {                                                                \
      unsigned long long t = __shfl_xor(w, SS, 64);                     \
      w = (lane & SS) ? ((w & ~(MLO)) | ((t >> SS) & (MLO)))            \
                      : ((w & (MLO)) | ((t & (MLO)) << SS));            \
    } while (0)
    BTSTEP(32, 0x00000000FFFFFFFFull);
    BTSTEP(16, 0x0000FFFF0000FFFFull);
    BTSTEP(8,  0x00FF00FF00FF00FFull);
    BTSTEP(4,  0x0F0F0F0F0F0F0F0Full);
    BTSTEP(2,  0x3333333333333333ull);
    BTSTEP(1,  0x5555555555555555ull);
#undef BTSTEP
    if ((lane >> 5) == h) {
      const int n = ((lane >> 1) << 7) + 2 * Lt + (lane & 1);
      cb[(size_t)n * 64 + Lp] = w;
    }
  }
}

// finalize u1 from partials: u = -log(S) (+1e9 if empty), pk_t = (tx,ty,u),
// ecnt census (64 blocks; batch uniform per wave since 4096 % 256 == 0).
__global__ __launch_bounds__(256) void u1fin_kernel(
    const float2* __restrict__ tlm, const float* __restrict__ S,
    float* __restrict__ u, float4* __restrict__ pk_t, int* __restrict__ ecnt)
{
  const int i = blockIdx.x * 256 + threadIdx.x;
  const float s = S[i];
  const float uv = (s == 0.0f) ? 1.0e9f : -__logf(s);
  u[i] = uv;
  float2 t = tlm[i];
  pk_t[i] = make_float4(t.x, t.y, uv, 0.0f);
  unsigned long long bal = __ballot(s == 0.0f);
  if ((threadIdx.x & 63) == 0) {
    int e = __popcll(bal);
    if (e) atomicAdd(&ecnt[i >> 12], e);
  }
}

// u[row] = -log(sum_j exp(logK_j + v[n_j])), +1e9 if no valid entries.
// One wave per row; 2-way software-pipelined ctz loop (2 scattered 16B loads
// in flight). No max pass: |t| << 87. Writes pk_t = (tx,ty,u).
__global__ __launch_bounds__(256) void lse_row_kernel(
    const float2* __restrict__ tlm,
    const float4* __restrict__ pk_s,
    const unsigned long long* __restrict__ row_bm,
    float* __restrict__ u, float4* __restrict__ pk_t)
{
  const int lane = threadIdx.x & 63;
  const int j    = blockIdx.x;
  const int row  = (j & 7) * 2048 + (j >> 3) * 4 + (threadIdx.x >> 6);
  const int b    = row >> 12;
  unsigned long long w = row_bm[(size_t)row * 64 + lane];
  const float2 a = tlm[row];
  const float4* __restrict__ ps = pk_s + (size_t)b * NN;
  float s_l = 0.0f;
  while (w) {
    int k0 = (int)__builtin_ctzll(w); w &= w - 1;
    int n0 = ((k0 >> 1) << 7) + 2 * lane + (k0 & 1);
    float4 p0 = ps[n0];
    if (w) {
      int k1 = (int)__builtin_ctzll(w); w &= w - 1;
      int n1 = ((k1 >> 1) << 7) + 2 * lane + (k1 & 1);
      float4 p1 = ps[n1];
      float dx0 = a.x - p0.x, dy0 = a.y - p0.y;
      float dx1 = a.x - p1.x, dy1 = a.y - p1.y;
      s_l += __expf(fmaf(dy0, dy0, dx0 * dx0) * kNegInvEps + p0.z);
      s_l += __expf(fmaf(dy1, dy1, dx1 * dx1) * kNegInvEps + p1.z);
    } else {
      float dx0 = a.x - p0.x, dy0 = a.y - p0.y;
      s_l += __expf(fmaf(dy0, dy0, dx0 * dx0) * kNegInvEps + p0.z);
    }
  }
  float ssum = wave_reduce_sum(s_l);
  if (lane == 0) {
    float uv = (ssum == 0.0f) ? 1.0e9f : -__logf(ssum);
    u[row] = uv;
    pk_t[row] = make_float4(a.x, a.y, uv, 0.0f);
  }
}

// v[col] = !sv ? 0 : -log(sum exp(t) + cc); +1e9 if both empty.
// 2-way pipelined; writes pk_s = (sx,sy,v).
__global__ __launch_bounds__(256) void lse_col_kernel(
    const float2* __restrict__ slm,
    const float4* __restrict__ pk_t,
    const unsigned long long* __restrict__ col_bm,
    const int* __restrict__ smask, const int* __restrict__ ecnt,
    float4* __restrict__ pk_s)
{
  const int lane = threadIdx.x & 63;
  const int j    = blockIdx.x;
  const int col  = (j & 7) * 2048 + (j >> 3) * 4 + (threadIdx.x >> 6);
  if (!smask[col]) {
    if (lane == 0)
      pk_s[col] = make_float4(1.0e9f, 1.0e9f, 0.0f, 0.0f);  // never read via bm
    return;
  }
  const int b = col >> 12;
  unsigned long long w = col_bm[(size_t)col * 64 + lane];
  const float2 a = slm[col];
  const float4* __restrict__ pt = pk_t + (size_t)b * MM;
  float s_l = 0.0f;
  while (w) {
    int k0 = (int)__builtin_ctzll(w); w &= w - 1;
    int m0 = ((k0 >> 1) << 7) + 2 * lane + (k0 & 1);
    float4 p0 = pt[m0];
    if (w) {
      int k1 = (int)__builtin_ctzll(w); w &= w - 1;
      int m1 = ((k1 >> 1) << 7) + 2 * lane + (k1 & 1);
      float4 p1 = pt[m1];
      float dx0 = a.x - p0.x, dy0 = a.y - p0.y;
      float dx1 = a.x - p1.x, dy1 = a.y - p1.y;
      s_l += __expf(fmaf(dy0, dy0, dx0 * dx0) * kNegInvEps + p0.z);
      s_l += __expf(fmaf(dy1, dy1, dx1 * dx1) * kNegInvEps + p1.z);
    } else {
      float dx0 = a.x - p0.x, dy0 = a.y - p0.y;
      s_l += __expf(fmaf(dy0, dy0, dx0 * dx0) * kNegInvEps + p0.z);
    }
  }
  float ssum = wave_reduce_sum(s_l);
  if (lane == 0) {
    float tot = ssum + (float)ecnt[b];   // contamination entries are exp(0)=1
    float vv = (tot == 0.0f) ? 1.0e9f : -__logf(tot);
    pk_s[col] = make_float4(a.x, a.y, vv, 0.0f);
  }
}

// out[row,:] = sum_j attn_j * feats[n_j,:], one block per row (at the
// 35TB/s L2 roof). Phase 1: 256 threads extract the row's bitmap (thread t
// owns the (t&3)-th 16-bit quarter of word t>>2), ONE packed 16B load per
// pair (sx,sy,v3), compute attn, append to LDS via atomic slot. Phase 2:
// 8 groups x 32 lanes gather feats float4 and reduce.
__global__ __launch_bounds__(256) void output3_kernel(
    const float2* __restrict__ tlm,
    const float4* __restrict__ pk_s,
    const unsigned long long* __restrict__ row_bm,
    const float* __restrict__ u,
    const float* __restrict__ feats, float* __restrict__ out)
{
  __shared__ float s_attn[1024];
  __shared__ unsigned short s_id[1024];
  __shared__ float4 s_red[256];
  __shared__ int s_cnt;

  const int j   = blockIdx.x;
  const int row = (j & 7) * 2048 + (j >> 3);
  const int tid = threadIdx.x;
  const int b   = row >> 12;
  if (tid == 0) s_cnt = 0;
  __syncthreads();

  {
    const int L  = tid >> 2;
    const int qp = tid & 3;
    unsigned long long w = row_bm[(size_t)row * 64 + L];
    unsigned wq = (unsigned)(unsigned short)(w >> (qp * 16));
    if (wq) {
      const float um = u[row];
      const float2 a = tlm[row];
      const float4* __restrict__ ps = pk_s + (size_t)b * NN;
      while (wq) {
        int kk = (int)__builtin_ctz(wq);
        wq &= wq - 1;
        int k = qp * 16 + kk;
        int n = ((k >> 1) << 7) + 2 * L + (k & 1);
        float4 p = ps[n];
        float dx = a.x - p.x, dy = a.y - p.y;
        float aw = __expf(fmaf(dy, dy, dx * dx) * kNegInvEps + um + p.z);
        int pos = atomicAdd(&s_cnt, 1);
        if (pos < 1024) { s_attn[pos] = aw; s_id[pos] = (unsigned short)n; }
      }
    }
  }
  __syncthreads();

  int cnt = s_cnt;
  if (cnt > 1024) cnt = 1024;             // realistic max ~330, never hit
  float4* op = (float4*)(out + (size_t)row * CC);
  if (cnt == 0) {                         // covers !tgt_valid and !has_source
    if (tid < 32) op[tid] = make_float4(0.f, 0.f, 0.f, 0.f);
    return;
  }

  const int g = tid >> 5, l = tid & 31;
  const float4* __restrict__ fb = (const float4*)(feats + (size_t)b * NN * CC);
  float4 acc = make_float4(0.f, 0.f, 0.f, 0.f);
  for (int jj = g; jj < cnt; jj += 8) {
    float aw = s_attn[jj];
    int   n  = s_id[jj];
    float4 f = fb[(size_t)n * 32 + l];
    acc.x = fmaf(aw, f.x, acc.x);
    acc.y = fmaf(aw, f.y, acc.y);
    acc.z = fmaf(aw, f.z, acc.z);
    acc.w = fmaf(aw, f.w, acc.w);
  }
  s_red[tid] = acc;
  __syncthreads();
  if (tid < 32) {
    float4 r = s_red[tid];
#pragma unroll
    for (int gg = 1; gg < 8; ++gg) {
      float4 p = s_red[gg * 32 + tid];
      r.x += p.x; r.y += p.y; r.z += p.z; r.w += p.w;
    }
    op[tid] = r;
  }
}

// ---------------------------------------------------------------------------
// FALLBACK PATH (round-1 kernels, ~128 KB workspace) — used if ws too small
// ---------------------------------------------------------------------------

__global__ __launch_bounds__(256) void init_v_kernel(float* __restrict__ v) {
  int i = blockIdx.x * 256 + threadIdx.x;
  if (i < BB * NN) v[i] = 0.0f;
}

__global__ __launch_bounds__(256) void u_update_kernel(
    const float* __restrict__ src_locs, const float* __restrict__ tgt_locs,
    const int* __restrict__ src_valid, const int* __restrict__ tgt_valid,
    const float* __restrict__ v, float* __restrict__ u)
{
  const int lane = threadIdx.x & 63;
  const int row  = blockIdx.x * 4 + (threadIdx.x >> 6);
  const int b    = row / MM;
  const float tx = tgt_locs[row * 2 + 0];
  const float ty = tgt_locs[row * 2 + 1];
  const bool  tv = tgt_valid[row] != 0;
  const float2* __restrict__ sl  = (const float2*)(src_locs + (size_t)b * NN * 2);
  const float*  __restrict__ vb  = v + (size_t)b * NN;
  const int*    __restrict__ svb = src_valid + (size_t)b * NN;
  float mx = -3.0e38f;
#pragma unroll 4
  for (int i = 0; i < NN / 64; ++i) {
    int n = i * 64 + lane;
    float2 s = sl[n];
    float dx = tx - s.x, dy = ty - s.y;
    float d2 = dx * dx + dy * dy;
    bool valid = (d2 < kThresh2) & tv & (svb[n] != 0);
    float t = (valid ? d2 * kNegInvEps : kNegInf) + vb[n];
    mx = fmaxf(mx, t);
  }
  mx = wave_reduce_max(mx);
  float s = 0.0f;
#pragma unroll 4
  for (int i = 0; i < NN / 64; ++i) {
    int n = i * 64 + lane;
    float2 sc = sl[n];
    float dx = tx - sc.x, dy = ty - sc.y;
    float d2 = dx * dx + dy * dy;
    bool valid = (d2 < kThresh2) & tv & (svb[n] != 0);
    float t = (valid ? d2 * kNegInvEps : kNegInf) + vb[n];
    s += __expf(t - mx);
  }
  s = wave_reduce_sum(s);
  if (lane == 0) u[row] = -(mx + __logf(s));
}

__global__ __launch_bounds__(256) void v_update_kernel(
    const float* __restrict__ src_locs, const float* __restrict__ tgt_locs,
    const int* __restrict__ src_valid, const int* __restrict__ tgt_valid,
    const float* __restrict__ u, float* __restrict__ v)
{
  const int lane = threadIdx.x & 63;
  const int col  = blockIdx.x * 4 + (threadIdx.x >> 6);
  const int b    = col / NN;
  const float sx = src_locs[col * 2 + 0];
  const float sy = src_locs[col * 2 + 1];
  const bool  sv = src_valid[col] != 0;
  const float2* __restrict__ tl  = (const float2*)(tgt_locs + (size_t)b * MM * 2);
  const float*  __restrict__ ub  = u + (size_t)b * MM;
  const int*    __restrict__ tvb = tgt_valid + (size_t)b * MM;
  float mx = -3.0e38f;
#pragma unroll 4
  for (int i = 0; i < MM / 64; ++i) {
    int m = i * 64 + lane;
    float2 t2 = tl[m];
    float dx = t2.x - sx, dy = t2.y - sy;
    float d2 = dx * dx + dy * dy;
    bool valid = (d2 < kThresh2) & sv & (tvb[m] != 0);
    float t = (valid ? d2 * kNegInvEps : kNegInf) + ub[m];
    mx = fmaxf(mx, t);
  }
  mx = wave_reduce_max(mx);
  float s = 0.0f;
#pragma unroll 4
  for (int i = 0; i < MM / 64; ++i) {
    int m = i * 64 + lane;
    float2 t2 = tl[m];
    float dx = t2.x - sx, dy = t2.y - sy;
    float d2 = dx * dx + dy * dy;
    bool valid = (d2 < kThresh2) & sv & (tvb[m] != 0);
    float t = (valid ? d2 * kNegInvEps : kNegInf) + ub[m];
    s += __expf(t - mx);
  }
  s = wave_reduce_sum(s);
  if (lane == 0) v[col] = sv ? -(mx + __logf(s)) : 0.0f;
}

__global__ __launch_bounds__(256) void output_kernel(
    const float* __restrict__ src_locs, const float* __restrict__ tgt_locs,
    const int* __restrict__ src_valid, const int* __restrict__ tgt_valid,
    const float* __restrict__ u, const float* __restrict__ v,
    const float* __restrict__ feats, float* __restrict__ out)
{
  __shared__ float s_attn[NN];
  __shared__ int   s_idx[NN];
  __shared__ int   s_cnt;
  __shared__ float s_part[CC];
  const int row = blockIdx.x;
  const int b   = row / MM;
  const int tid = threadIdx.x;
  if (tid == 0) s_cnt = 0;
  __syncthreads();
  const float tx = tgt_locs[row * 2 + 0];
  const float ty = tgt_locs[row * 2 + 1];
  const bool  tv = tgt_valid[row] != 0;
  const float um = u[row];
  const float2* __restrict__ sl  = (const float2*)(src_locs + (size_t)b * NN * 2);
  const float*  __restrict__ vb  = v + (size_t)b * NN;
  const int*    __restrict__ svb = src_valid + (size_t)b * NN;
#pragma unroll 4
  for (int i = 0; i < NN / 256; ++i) {
    int n = i * 256 + tid;
    float2 s = sl[n];
    float dx = tx - s.x, dy = ty - s.y;
    float d2 = dx * dx + dy * dy;
    bool valid = (d2 < kThresh2) & tv & (svb[n] != 0);
    if (valid) {
      float a = __expf((d2 * kNegInvEps + um) + vb[n]);
      int p = atomicAdd(&s_cnt, 1);
      s_attn[p] = a;
      s_idx[p]  = n;
    }
  }
  __syncthreads();
  const int cnt = s_cnt;
  const int g = tid >> 7;
  const int c = tid & (CC - 1);
  const float* __restrict__ fb = feats + (size_t)b * NN * CC;
  float acc = 0.0f;
  for (int j = g; j < cnt; j += 2) {
    float a = s_attn[j];
    int   n = s_idx[j];
    acc = fmaf(a, fb[(size_t)n * CC + c], acc);
  }
  if (g == 1) s_part[c] = acc;
  __syncthreads();
  if (g == 0) {
    float r = (cnt > 0) ? (acc + s_part[c]) : 0.0f;
    out[(size_t)row * CC + c] = r;
  }
}

// ---------------------------------------------------------------------------

extern "C" void kernel_launch(void* const* d_in, const int* in_sizes, int n_in,
                              void* d_out, int out_size, void* d_ws, size_t ws_size,
                              hipStream_t stream) {
  const float* feats = (const float*)d_in[0];
  const float* sloc  = (const float*)d_in[1];
  const float* tloc  = (const float*)d_in[2];
  const int*   smask = (const int*)d_in[3];
  const int*   tmask = (const int*)d_in[4];
  float* out = (float*)d_out;

  // workspace layout (fast path): ~18 MB
  char* p = (char*)d_ws;
  float* u_   = (float*)p;            p += (size_t)BB * MM * 4;
  float* S_   = (float*)p;            p += (size_t)BB * MM * 4;
  int* ecnt   = (int*)p;              p += 256;
  float2* slm = (float2*)p;           p += (size_t)BB * NN * 8;
  float2* tlm = (float2*)p;           p += (size_t)BB * MM * 8;
  float4* pk_s = (float4*)p;          p += (size_t)BB * NN * 16;
  float4* pk_t = (float4*)p;          p += (size_t)BB * MM * 16;
  unsigned long long* row_bm = (unsigned long long*)p; p += (size_t)BB * MM * 64 * 8;
  unsigned long long* col_bm = (unsigned long long*)p; p += (size_t)BB * NN * 64 * 8;
  size_t required = (size_t)(p - (char*)d_ws);

  if (ws_size >= required) {
    prep_kernel<<<(BB * NN + 255) / 256, 256, 0, stream>>>(
        sloc, tloc, smask, tmask, S_, ecnt, slm, tlm, pk_s);
    // split sweep: 512 blocks (2/CU, 8 waves/SIMD), halves write u32 row
    // half-words + complete col words for their partner range + u1 partials
    sweep11_kernel<<<BB * 64 * 2, 1024, 0, stream>>>(
        slm, tlm, row_bm, col_bm, S_);
    u1fin_kernel<<<BB * MM / 256, 256, 0, stream>>>(
        tlm, S_, u_, pk_t, ecnt);
    // chain: v1, u2, v2, u3, v3 (5 stream dispatches -- measured cheaper
    // than any fusion: grid.sync costs ~135us/sync, R14)
    for (int it = 0; it < 3; ++it) {
      lse_col_kernel<<<BB * NN / 4, 256, 0, stream>>>(slm, pk_t, col_bm,
                                                      smask, ecnt, pk_s);
      if (it < 2)
        lse_row_kernel<<<BB * MM / 4, 256, 0, stream>>>(tlm, pk_s, row_bm,
                                                        u_, pk_t);
    }
    output3_kernel<<<BB * MM, 256, 0, stream>>>(tlm, pk_s, row_bm,
                                                u_, feats, out);
  } else {
    // fallback: round-1 path (dense re-sweeps), needs only 128 KB
    float* u = (float*)d_ws;
    float* v = u + (size_t)BB * MM;
    init_v_kernel<<<(BB * NN + 255) / 256, 256, 0, stream>>>(v);
    for (int it = 0; it < 3; ++it) {
      u_update_kernel<<<BB * MM / 4, 256, 0, stream>>>(sloc, tloc, smask, tmask, v, u);
      v_update_kernel<<<BB * NN / 4, 256, 0, stream>>>(sloc, tloc, smask, tmask, u, v);
    }
    output_kernel<<<BB * MM, 256, 0, stream>>>(sloc, tloc, smask, tmask, u, v, feats, out);
  }
}

// Round 16
// 188.066 us; speedup vs baseline: 4.4694x; 1.0073x over previous
//
#include <hip/hip_runtime.h>

// GeometryOptimalTransport: B=4, N=M=4096, C=128
// Sinkhorn (3 iters) over log_K(m,n) = -dist2/eps masked to -1e9, then
// attn-weighted gather of source feats.
//
// R2: validity is iteration-invariant -> precompute adjacency once; run all
// lse updates + output on the ~3% dense structure. Finite NEG_INF=-1e9
// contamination is closed-form:
//   - row with 0 valid entries => u = +1e9 EXACTLY (ulp(1e9)=64)
//   - such rows contribute exp(0) to EVERY column lse => per-batch count cc
//   - all other invalid entries underflow to exactly 0 in fp32.
// Journal (keep for future sessions):
//   - compaction in ANY form costs ~60us (R5/R6) -> permuted bitmap instead
//     (bit k of lane L's word <=> partner n=(k>>1)*128+2L+(k&1))
//   - sorted 4-row output REGRESSED (R12): gather set 118KB >> 32KB L1.
//   - 128-thr lse split NEUTRAL (R13): divergent tail was not the gate.
//   - cooperative grid.sync costs ~135us PER SYNC on MI355X (R14). NEVER.
//   - scattered-LINE count minor (R16: -8.5us); packed float4 kept.
//   - TLP was the real sweep lever (R17 CONFIRMED: 4->8 waves/SIMD took
//     sweep 72 -> ~45us; total 223 -> 189). All kernels now at max occupancy.
//   - output3 at the measured ~36 TB/s L2 gather ceiling (feats L2-resident:
//     FETCH 8.7MB = one HBM pass).
// R19 (this round): extend the validated MLP lever: lse gather loop 2-way ->
// 4-way pipelined (extract up to 4 bit-indices, issue 4 packed loads, then
// consume). Same math/commutative sum. Predict ~1-2us per lse dispatch.

constexpr int   BB = 4;
constexpr int   NN = 4096;
constexpr int   MM = 4096;
constexpr int   CC = 128;
constexpr float kNegInf    = -1000000000.0f;
constexpr float kThresh2   = 0.04f;                 // 0.2^2
constexpr float kNegInvEps = -(1.0f / 0.01000001f); // -(1/(EPSILON+1e-8))

__device__ inline float wave_reduce_sum(float x) {
#pragma unroll
  for (int off = 32; off > 0; off >>= 1)
    x += __shfl_xor(x, off, 64);
  return x;
}
__device__ inline float wave_reduce_max(float x) {
#pragma unroll
  for (int off = 32; off > 0; off >>= 1)
    x = fmaxf(x, __shfl_xor(x, off, 64));
  return x;
}

// 4-way pipelined bitmap-gather lse body: accumulates sum of
// exp(dist2(a, p.xy) * c + p.z) over set bits of w. IDX maps bit k -> index.
__device__ inline float lse_gather4(unsigned long long w, int lane,
                                    float2 a, const float4* __restrict__ pp)
{
  float s_l = 0.0f;
  while (w) {
    int c = 1;
    int k0 = (int)__builtin_ctzll(w); w &= w - 1;
    float4 p0 = pp[((k0 >> 1) << 7) + 2 * lane + (k0 & 1)];
    float4 p1, p2, p3;
    if (w) {
      int k1 = (int)__builtin_ctzll(w); w &= w - 1;
      p1 = pp[((k1 >> 1) << 7) + 2 * lane + (k1 & 1)];
      c = 2;
      if (w) {
        int k2 = (int)__builtin_ctzll(w); w &= w - 1;
        p2 = pp[((k2 >> 1) << 7) + 2 * lane + (k2 & 1)];
        c = 3;
        if (w) {
          int k3 = (int)__builtin_ctzll(w); w &= w - 1;
          p3 = pp[((k3 >> 1) << 7) + 2 * lane + (k3 & 1)];
          c = 4;
        }
      }
    }
    {
      float dx = a.x - p0.x, dy = a.y - p0.y;
      s_l += __expf(fmaf(dy, dy, dx * dx) * kNegInvEps + p0.z);
    }
    if (c > 1) {
      float dx = a.x - p1.x, dy = a.y - p1.y;
      s_l += __expf(fmaf(dy, dy, dx * dx) * kNegInvEps + p1.z);
    }
    if (c > 2) {
      float dx = a.x - p2.x, dy = a.y - p2.y;
      s_l += __expf(fmaf(dy, dy, dx * dx) * kNegInvEps + p2.z);
    }
    if (c > 3) {
      float dx = a.x - p3.x, dy = a.y - p3.y;
      s_l += __expf(fmaf(dy, dy, dx * dx) * kNegInvEps + p3.z);
    }
  }
  return s_l;
}

// ---------------------------------------------------------------------------
// FAST PATH (needs ~18 MB workspace)
// ---------------------------------------------------------------------------

// zero u1-partials S + ecnt, fold masks into locs (invalid -> far sentinel;
// DIFFERENT sentinels per side so two invalid points are never "close");
// init packed source (sx, sy, v=0).
__global__ __launch_bounds__(256) void prep_kernel(
    const float* __restrict__ sloc, const float* __restrict__ tloc,
    const int* __restrict__ sm, const int* __restrict__ tm,
    float* __restrict__ S, int* __restrict__ ecnt,
    float2* __restrict__ slm, float2* __restrict__ tlm,
    float4* __restrict__ pk_s)
{
  int i = blockIdx.x * 256 + threadIdx.x;
  if (i < BB * NN) {
    S[i] = 0.0f;
    float2 s = ((const float2*)sloc)[i];
    float2 sv = sm[i] ? s : make_float2(1.0e9f, 1.0e9f);
    slm[i] = sv;
    pk_s[i] = make_float4(sv.x, sv.y, 0.0f, 0.0f);
    float2 t = ((const float2*)tloc)[i];
    tlm[i] = tm[i] ? t : make_float2(3.0e9f, 3.0e9f);
    if (i < BB) ecnt[i] = 0;
  }
}

// Split sweep + u1-partials + bit-transpose. One block per (b, L', h):
// 512 blocks (2/CU -> 8 waves/SIMD = max occupancy), 1024 thr = 16 waves,
// wave wid owns rows {base, base+1, base+128, base+129}, base = wid*256+2L'.
// Half h tests partners [h*2048, (h+1)*2048) in 16 iters; mask bits land in
// the h-th u32 of the row word (bit k=32h+2*ii+p <=> n=(16h+ii)*128+2L+p).
// Row halves stored as u32 (non-overlapping). u1 partial sums atomicAdd
// into S[row]. Butterfly runs on the shifted half-word tile; output lanes
// kap in [32h, 32h+32) hold COMPLETE col words and are written exactly once
// across the two h-blocks.
__global__ __launch_bounds__(1024) void sweep11_kernel(
    const float2* __restrict__ slm, const float2* __restrict__ tlm,
    unsigned long long* __restrict__ row_bm,
    unsigned long long* __restrict__ col_bm,
    float* __restrict__ S)
{
  __shared__ unsigned long long tile[64 * 64];   // 32 KB

  const int blk  = blockIdx.x;
  const int b    = blk >> 7;
  const int Lp   = (blk >> 1) & 63;              // L'
  const int h    = blk & 1;
  const int tid  = threadIdx.x;
  const int lane = tid & 63;
  const int wid  = tid >> 6;                     // 0..15
  const int base = b * 4096 + wid * 256 + 2 * Lp;
  const int ra = base, rb = base + 1, rc = base + 128, rd = base + 129;

  const float2 a0 = tlm[ra];
  const float2 a1 = tlm[rb];
  const float2 a2 = tlm[rc];
  const float2 a3 = tlm[rd];
  const float4* __restrict__ bl4 =
      (const float4*)(slm + (size_t)b * 4096) + (size_t)h * 16 * 64;

  unsigned m0 = 0, m1 = 0, m2 = 0, m3 = 0;
  float s0 = 0.0f, s1 = 0.0f, s2 = 0.0f, s3 = 0.0f;
#pragma unroll 8
  for (int ii = 0; ii < 16; ++ii) {
    float4 q = bl4[ii * 64 + lane];
#define SWTEST(aa, mm, ss)                                         \
    do {                                                           \
      float dx0 = (aa).x - q.x, dy0 = (aa).y - q.y;                \
      float dx1 = (aa).x - q.z, dy1 = (aa).y - q.w;                \
      float d0 = fmaf(dy0, dy0, dx0 * dx0);                        \
      float d1 = fmaf(dy1, dy1, dx1 * dx1);                        \
      bool p0 = d0 < kThresh2;                                     \
      bool p1 = d1 < kThresh2;                                     \
      mm = (mm >> 2) | (p0 ? (1u << 30) : 0u)                      \
                     | (p1 ? (1u << 31) : 0u);                     \
      float e0 = __expf(d0 * kNegInvEps);                          \
      float e1 = __expf(d1 * kNegInvEps);                          \
      ss += p0 ? e0 : 0.0f;                                        \
      ss += p1 ? e1 : 0.0f;                                        \
    } while (0)
    SWTEST(a0, m0, s0);
    SWTEST(a1, m1, s1);
    SWTEST(a2, m2, s2);
    SWTEST(a3, m3, s3);
#undef SWTEST
  }

  // row halves: u32 at word offset h (little-endian: h=0 -> bits 0..31)
  unsigned* __restrict__ rb32 = (unsigned*)row_bm;
  rb32[((size_t)ra * 64 + lane) * 2 + h] = m0;
  rb32[((size_t)rb * 64 + lane) * 2 + h] = m1;
  rb32[((size_t)rc * 64 + lane) * 2 + h] = m2;
  rb32[((size_t)rd * 64 + lane) * 2 + h] = m3;

  const int sh = 32 * h;
  const unsigned long long w0 = (unsigned long long)m0 << sh;
  const unsigned long long w1 = (unsigned long long)m1 << sh;
  const unsigned long long w2 = (unsigned long long)m2 << sh;
  const unsigned long long w3 = (unsigned long long)m3 << sh;

  // stage tile rows (rho = wid*4 + j), rotated slot (lane+rho)&63
  {
    const int r0 = wid * 4;
    tile[(r0 + 0) * 64 + ((lane + r0 + 0) & 63)] = w0;
    tile[(r0 + 1) * 64 + ((lane + r0 + 1) & 63)] = w1;
    tile[(r0 + 2) * 64 + ((lane + r0 + 2) & 63)] = w2;
    tile[(r0 + 3) * 64 + ((lane + r0 + 3) & 63)] = w3;
  }

  // u1 partial sums (both halves add; finalize kernel takes -log)
  s0 = wave_reduce_sum(s0);
  s1 = wave_reduce_sum(s1);
  s2 = wave_reduce_sum(s2);
  s3 = wave_reduce_sum(s3);
  if (lane == 0) {
    if (s0 != 0.0f) atomicAdd(&S[ra], s0);
    if (s1 != 0.0f) atomicAdd(&S[rb], s1);
    if (s2 != 0.0f) atomicAdd(&S[rc], s2);
    if (s3 != 0.0f) atomicAdd(&S[rd], s3);
  }
  __syncthreads();

  // transpose: wave wid handles Lt = wid*4..+3 (verified butterfly from R9).
  // Only output lanes kap with (kap>>5)==h carry this half's (complete)
  // col words; each col word is written by exactly one h-block.
  unsigned long long* __restrict__ cb = col_bm + ((size_t)b << 12) * 64;
#pragma unroll
  for (int i = 0; i < 4; ++i) {
    const int Lt = wid * 4 + i;
    unsigned long long w = tile[lane * 64 + ((Lt + lane) & 63)];
#define BTSTEP(SS, MLO)                                                 \
    do {                                                                \
      unsigned long long t = __shfl_xor(w, SS, 64);                     \
      w = (lane & SS) ? ((w & ~(MLO)) | ((t >> SS) & (MLO)))            \
                      : ((w & (MLO)) | ((t & (MLO)) << SS));            \
    } while (0)
    BTSTEP(32, 0x00000000FFFFFFFFull);
    BTSTEP(16, 0x0000FFFF0000FFFFull);
    BTSTEP(8,  0x00FF00FF00FF00FFull);
    BTSTEP(4,  0x0F0F0F0F0F0F0F0Full);
    BTSTEP(2,  0x3333333333333333ull);
    BTSTEP(1,  0x5555555555555555ull);
#undef BTSTEP
    if ((lane >> 5) == h) {
      const int n = ((lane >> 1) << 7) + 2 * Lt + (lane & 1);
      cb[(size_t)n * 64 + Lp] = w;
    }
  }
}

// finalize u1 from partials: u = -log(S) (+1e9 if empty), pk_t = (tx,ty,u),
// ecnt census (64 blocks; batch uniform per wave since 4096 % 256 == 0).
__global__ __launch_bounds__(256) void u1fin_kernel(
    const float2* __restrict__ tlm, const float* __restrict__ S,
    float* __restrict__ u, float4* __restrict__ pk_t, int* __restrict__ ecnt)
{
  const int i = blockIdx.x * 256 + threadIdx.x;
  const float s = S[i];
  const float uv = (s == 0.0f) ? 1.0e9f : -__logf(s);
  u[i] = uv;
  float2 t = tlm[i];
  pk_t[i] = make_float4(t.x, t.y, uv, 0.0f);
  unsigned long long bal = __ballot(s == 0.0f);
  if ((threadIdx.x & 63) == 0) {
    int e = __popcll(bal);
    if (e) atomicAdd(&ecnt[i >> 12], e);
  }
}

// u[row] = -log(sum_j exp(logK_j + v[n_j])), +1e9 if no valid entries.
// One wave per row; 4-way pipelined gather. No max pass: |t| << 87.
// Writes pk_t = (tx,ty,u).
__global__ __launch_bounds__(256) void lse_row_kernel(
    const float2* __restrict__ tlm,
    const float4* __restrict__ pk_s,
    const unsigned long long* __restrict__ row_bm,
    float* __restrict__ u, float4* __restrict__ pk_t)
{
  const int lane = threadIdx.x & 63;
  const int j    = blockIdx.x;
  const int row  = (j & 7) * 2048 + (j >> 3) * 4 + (threadIdx.x >> 6);
  const int b    = row >> 12;
  unsigned long long w = row_bm[(size_t)row * 64 + lane];
  const float2 a = tlm[row];
  float s_l = lse_gather4(w, lane, a, pk_s + (size_t)b * NN);
  float ssum = wave_reduce_sum(s_l);
  if (lane == 0) {
    float uv = (ssum == 0.0f) ? 1.0e9f : -__logf(ssum);
    u[row] = uv;
    pk_t[row] = make_float4(a.x, a.y, uv, 0.0f);
  }
}

// v[col] = !sv ? 0 : -log(sum exp(t) + cc); +1e9 if both empty.
// 4-way pipelined; writes pk_s = (sx,sy,v).
__global__ __launch_bounds__(256) void lse_col_kernel(
    const float2* __restrict__ slm,
    const float4* __restrict__ pk_t,
    const unsigned long long* __restrict__ col_bm,
    const int* __restrict__ smask, const int* __restrict__ ecnt,
    float4* __restrict__ pk_s)
{
  const int lane = threadIdx.x & 63;
  const int j    = blockIdx.x;
  const int col  = (j & 7) * 2048 + (j >> 3) * 4 + (threadIdx.x >> 6);
  if (!smask[col]) {
    if (lane == 0)
      pk_s[col] = make_float4(1.0e9f, 1.0e9f, 0.0f, 0.0f);  // never read via bm
    return;
  }
  const int b = col >> 12;
  unsigned long long w = col_bm[(size_t)col * 64 + lane];
  const float2 a = slm[col];
  float s_l = lse_gather4(w, lane, a, pk_t + (size_t)b * MM);
  float ssum = wave_reduce_sum(s_l);
  if (lane == 0) {
    float tot = ssum + (float)ecnt[b];   // contamination entries are exp(0)=1
    float vv = (tot == 0.0f) ? 1.0e9f : -__logf(tot);
    pk_s[col] = make_float4(a.x, a.y, vv, 0.0f);
  }
}

// out[row,:] = sum_j attn_j * feats[n_j,:], one block per row (at the
// ~36 TB/s L2 gather roof; feats L2-resident, FETCH = one 8MB HBM pass).
// Phase 1: 256 threads extract the row's bitmap (thread t owns the (t&3)-th
// 16-bit quarter of word t>>2), ONE packed 16B load per pair (sx,sy,v3),
// compute attn, append to LDS via atomic slot. Phase 2: 8 groups x 32 lanes
// gather feats float4 and reduce.
__global__ __launch_bounds__(256) void output3_kernel(
    const float2* __restrict__ tlm,
    const float4* __restrict__ pk_s,
    const unsigned long long* __restrict__ row_bm,
    const float* __restrict__ u,
    const float* __restrict__ feats, float* __restrict__ out)
{
  __shared__ float s_attn[1024];
  __shared__ unsigned short s_id[1024];
  __shared__ float4 s_red[256];
  __shared__ int s_cnt;

  const int j   = blockIdx.x;
  const int row = (j & 7) * 2048 + (j >> 3);
  const int tid = threadIdx.x;
  const int b   = row >> 12;
  if (tid == 0) s_cnt = 0;
  __syncthreads();

  {
    const int L  = tid >> 2;
    const int qp = tid & 3;
    unsigned long long w = row_bm[(size_t)row * 64 + L];
    unsigned wq = (unsigned)(unsigned short)(w >> (qp * 16));
    if (wq) {
      const float um = u[row];
      const float2 a = tlm[row];
      const float4* __restrict__ ps = pk_s + (size_t)b * NN;
      while (wq) {
        int kk = (int)__builtin_ctz(wq);
        wq &= wq - 1;
        int k = qp * 16 + kk;
        int n = ((k >> 1) << 7) + 2 * L + (k & 1);
        float4 p = ps[n];
        float dx = a.x - p.x, dy = a.y - p.y;
        float aw = __expf(fmaf(dy, dy, dx * dx) * kNegInvEps + um + p.z);
        int pos = atomicAdd(&s_cnt, 1);
        if (pos < 1024) { s_attn[pos] = aw; s_id[pos] = (unsigned short)n; }
      }
    }
  }
  __syncthreads();

  int cnt = s_cnt;
  if (cnt > 1024) cnt = 1024;             // realistic max ~330, never hit
  float4* op = (float4*)(out + (size_t)row * CC);
  if (cnt == 0) {                         // covers !tgt_valid and !has_source
    if (tid < 32) op[tid] = make_float4(0.f, 0.f, 0.f, 0.f);
    return;
  }

  const int g = tid >> 5, l = tid & 31;
  const float4* __restrict__ fb = (const float4*)(feats + (size_t)b * NN * CC);
  float4 acc = make_float4(0.f, 0.f, 0.f, 0.f);
  for (int jj = g; jj < cnt; jj += 8) {
    float aw = s_attn[jj];
    int   n  = s_id[jj];
    float4 f = fb[(size_t)n * 32 + l];
    acc.x = fmaf(aw, f.x, acc.x);
    acc.y = fmaf(aw, f.y, acc.y);
    acc.z = fmaf(aw, f.z, acc.z);
    acc.w = fmaf(aw, f.w, acc.w);
  }
  s_red[tid] = acc;
  __syncthreads();
  if (tid < 32) {
    float4 r = s_red[tid];
#pragma unroll
    for (int gg = 1; gg < 8; ++gg) {
      float4 p = s_red[gg * 32 + tid];
      r.x += p.x; r.y += p.y; r.z += p.z; r.w += p.w;
    }
    op[tid] = r;
  }
}

// ---------------------------------------------------------------------------
// FALLBACK PATH (round-1 kernels, ~128 KB workspace) — used if ws too small
// ---------------------------------------------------------------------------

__global__ __launch_bounds__(256) void init_v_kernel(float* __restrict__ v) {
  int i = blockIdx.x * 256 + threadIdx.x;
  if (i < BB * NN) v[i] = 0.0f;
}

__global__ __launch_bounds__(256) void u_update_kernel(
    const float* __restrict__ src_locs, const float* __restrict__ tgt_locs,
    const int* __restrict__ src_valid, const int* __restrict__ tgt_valid,
    const float* __restrict__ v, float* __restrict__ u)
{
  const int lane = threadIdx.x & 63;
  const int row  = blockIdx.x * 4 + (threadIdx.x >> 6);
  const int b    = row / MM;
  const float tx = tgt_locs[row * 2 + 0];
  const float ty = tgt_locs[row * 2 + 1];
  const bool  tv = tgt_valid[row] != 0;
  const float2* __restrict__ sl  = (const float2*)(src_locs + (size_t)b * NN * 2);
  const float*  __restrict__ vb  = v + (size_t)b * NN;
  const int*    __restrict__ svb = src_valid + (size_t)b * NN;
  float mx = -3.0e38f;
#pragma unroll 4
  for (int i = 0; i < NN / 64; ++i) {
    int n = i * 64 + lane;
    float2 s = sl[n];
    float dx = tx - s.x, dy = ty - s.y;
    float d2 = dx * dx + dy * dy;
    bool valid = (d2 < kThresh2) & tv & (svb[n] != 0);
    float t = (valid ? d2 * kNegInvEps : kNegInf) + vb[n];
    mx = fmaxf(mx, t);
  }
  mx = wave_reduce_max(mx);
  float s = 0.0f;
#pragma unroll 4
  for (int i = 0; i < NN / 64; ++i) {
    int n = i * 64 + lane;
    float2 sc = sl[n];
    float dx = tx - sc.x, dy = ty - sc.y;
    float d2 = dx * dx + dy * dy;
    bool valid = (d2 < kThresh2) & tv & (svb[n] != 0);
    float t = (valid ? d2 * kNegInvEps : kNegInf) + vb[n];
    s += __expf(t - mx);
  }
  s = wave_reduce_sum(s);
  if (lane == 0) u[row] = -(mx + __logf(s));
}

__global__ __launch_bounds__(256) void v_update_kernel(
    const float* __restrict__ src_locs, const float* __restrict__ tgt_locs,
    const int* __restrict__ src_valid, const int* __restrict__ tgt_valid,
    const float* __restrict__ u, float* __restrict__ v)
{
  const int lane = threadIdx.x & 63;
  const int col  = blockIdx.x * 4 + (threadIdx.x >> 6);
  const int b    = col / NN;
  const float sx = src_locs[col * 2 + 0];
  const float sy = src_locs[col * 2 + 1];
  const bool  sv = src_valid[col] != 0;
  const float2* __restrict__ tl  = (const float2*)(tgt_locs + (size_t)b * MM * 2);
  const float*  __restrict__ ub  = u + (size_t)b * MM;
  const int*    __restrict__ tvb = tgt_valid + (size_t)b * MM;
  float mx = -3.0e38f;
#pragma unroll 4
  for (int i = 0; i < MM / 64; ++i) {
    int m = i * 64 + lane;
    float2 t2 = tl[m];
    float dx = t2.x - sx, dy = t2.y - sy;
    float d2 = dx * dx + dy * dy;
    bool valid = (d2 < kThresh2) & sv & (tvb[m] != 0);
    float t = (valid ? d2 * kNegInvEps : kNegInf) + ub[m];
    mx = fmaxf(mx, t);
  }
  mx = wave_reduce_max(mx);
  float s = 0.0f;
#pragma unroll 4
  for (int i = 0; i < MM / 64; ++i) {
    int m = i * 64 + lane;
    float2 t2 = tl[m];
    float dx = t2.x - sx, dy = t2.y - sy;
    float d2 = dx * dx + dy * dy;
    bool valid = (d2 < kThresh2) & sv & (tvb[m] != 0);
    float t = (valid ? d2 * kNegInvEps : kNegInf) + ub[m];
    s += __expf(t - mx);
  }
  s = wave_reduce_sum(s);
  if (lane == 0) v[col] = sv ? -(mx + __logf(s)) : 0.0f;
}

__global__ __launch_bounds__(256) void output_kernel(
    const float* __restrict__ src_locs, const float* __restrict__ tgt_locs,
    const int* __restrict__ src_valid, const int* __restrict__ tgt_valid,
    const float* __restrict__ u, const float* __restrict__ v,
    const float* __restrict__ feats, float* __restrict__ out)
{
  __shared__ float s_attn[NN];
  __shared__ int   s_idx[NN];
  __shared__ int   s_cnt;
  __shared__ float s_part[CC];
  const int row = blockIdx.x;
  const int b   = row / MM;
  const int tid = threadIdx.x;
  if (tid == 0) s_cnt = 0;
  __syncthreads();
  const float tx = tgt_locs[row * 2 + 0];
  const float ty = tgt_locs[row * 2 + 1];
  const bool  tv = tgt_valid[row] != 0;
  const float um = u[row];
  const float2* __restrict__ sl  = (const float2*)(src_locs + (size_t)b * NN * 2);
  const float*  __restrict__ vb  = v + (size_t)b * NN;
  const int*    __restrict__ svb = src_valid + (size_t)b * NN;
#pragma unroll 4
  for (int i = 0; i < NN / 256; ++i) {
    int n = i * 256 + tid;
    float2 s = sl[n];
    float dx = tx - s.x, dy = ty - s.y;
    float d2 = dx * dx + dy * dy;
    bool valid = (d2 < kThresh2) & tv & (svb[n] != 0);
    if (valid) {
      float a = __expf((d2 * kNegInvEps + um) + vb[n]);
      int p = atomicAdd(&s_cnt, 1);
      s_attn[p] = a;
      s_idx[p]  = n;
    }
  }
  __syncthreads();
  const int cnt = s_cnt;
  const int g = tid >> 7;
  const int c = tid & (CC - 1);
  const float* __restrict__ fb = feats + (size_t)b * NN * CC;
  float acc = 0.0f;
  for (int j = g; j < cnt; j += 2) {
    float a = s_attn[j];
    int   n = s_idx[j];
    acc = fmaf(a, fb[(size_t)n * CC + c], acc);
  }
  if (g == 1) s_part[c] = acc;
  __syncthreads();
  if (g == 0) {
    float r = (cnt > 0) ? (acc + s_part[c]) : 0.0f;
    out[(size_t)row * CC + c] = r;
  }
}

// ---------------------------------------------------------------------------

extern "C" void kernel_launch(void* const* d_in, const int* in_sizes, int n_in,
                              void* d_out, int out_size, void* d_ws, size_t ws_size,
                              hipStream_t stream) {
  const float* feats = (const float*)d_in[0];
  const float* sloc  = (const float*)d_in[1];
  const float* tloc  = (const float*)d_in[2];
  const int*   smask = (const int*)d_in[3];
  const int*   tmask = (const int*)d_in[4];
  float* out = (float*)d_out;

  // workspace layout (fast path): ~18 MB
  char* p = (char*)d_ws;
  float* u_   = (float*)p;            p += (size_t)BB * MM * 4;
  float* S_   = (float*)p;            p += (size_t)BB * MM * 4;
  int* ecnt   = (int*)p;              p += 256;
  float2* slm = (float2*)p;           p += (size_t)BB * NN * 8;
  float2* tlm = (float2*)p;           p += (size_t)BB * MM * 8;
  float4* pk_s = (float4*)p;          p += (size_t)BB * NN * 16;
  float4* pk_t = (float4*)p;          p += (size_t)BB * MM * 16;
  unsigned long long* row_bm = (unsigned long long*)p; p += (size_t)BB * MM * 64 * 8;
  unsigned long long* col_bm = (unsigned long long*)p; p += (size_t)BB * NN * 64 * 8;
  size_t required = (size_t)(p - (char*)d_ws);

  if (ws_size >= required) {
    prep_kernel<<<(BB * NN + 255) / 256, 256, 0, stream>>>(
        sloc, tloc, smask, tmask, S_, ecnt, slm, tlm, pk_s);
    // split sweep: 512 blocks (2/CU, 8 waves/SIMD = max), halves write u32
    // row half-words + complete col words for their range + u1 partials
    sweep11_kernel<<<BB * 64 * 2, 1024, 0, stream>>>(
        slm, tlm, row_bm, col_bm, S_);
    u1fin_kernel<<<BB * MM / 256, 256, 0, stream>>>(
        tlm, S_, u_, pk_t, ecnt);
    // chain: v1, u2, v2, u3, v3 (5 stream dispatches -- measured cheaper
    // than any fusion: grid.sync costs ~135us/sync, R14)
    for (int it = 0; it < 3; ++it) {
      lse_col_kernel<<<BB * NN / 4, 256, 0, stream>>>(slm, pk_t, col_bm,
                                                      smask, ecnt, pk_s);
      if (it < 2)
        lse_row_kernel<<<BB * MM / 4, 256, 0, stream>>>(tlm, pk_s, row_bm,
                                                        u_, pk_t);
    }
    output3_kernel<<<BB * MM, 256, 0, stream>>>(tlm, pk_s, row_bm,
                                                u_, feats, out);
  } else {
    // fallback: round-1 path (dense re-sweeps), needs only 128 KB
    float* u = (float*)d_ws;
    float* v = u + (size_t)BB * MM;
    init_v_kernel<<<(BB * NN + 255) / 256, 256, 0, stream>>>(v);
    for (int it = 0; it < 3; ++it) {
      u_update_kernel<<<BB * MM / 4, 256, 0, stream>>>(sloc, tloc, smask, tmask, v, u);
      v_update_kernel<<<BB * NN / 4, 256, 0, stream>>>(sloc, tloc, smask, tmask, u, v);
    }
    output_kernel<<<BB * MM, 256, 0, stream>>>(sloc, tloc, smask, tmask, u, v, feats, out);
  }
}